// Round 6
// baseline (646.423 us; speedup 1.0000x reference)
//
#include <hip/hip_runtime.h>

// VectorQuantizerEMA  N=32768 K=8192 D=256  fp32
// Outputs: z_q_st[N*D], commitment[1], idx[N], new_embed[K*D], new_count[K], new_avg[K*D]
//
// Single full fp16 MFMA score GEMM (z16 * (w*2^14)16):
//   score_min: 256x256 tile, BK=64, 8 waves, 8-phase counted-vmcnt schedule
//              (T3+T4+T5): per phase {stage quarter-unit for next K-tile;
//              vmcnt(6); barrier; ds_read quadrant; setprio(1); 16 MFMA;
//              setprio(0); barrier}. Loads stay in flight across barriers
//              (never drained to 0 in the main loop). Per-fragment K-chain is
//              the same 8 chained 16x16x32 MFMAs in increasing d as before ->
//              tmin BIT-IDENTICAL to the old 128^2 kernel (MFMA output is
//              schedule-independent; min is an exact op). Per-(row,128-code-
//              tile) min -> tmin[ntile][row].
//   rowmin_k:  thr[m] = min over 64 tile-mins + WWIN.
//   append_k:  512 blocks: 16-bit survivor masks, block prefix-scan, ONE
//              global atomicAdd per block.
//   score_gather: gathered-row 128x128 MFMA re-score ONLY for surviving pairs
//              (same per-fragment K-chain -> bit-identical scores);
//              block-aggregated insert (one atomicAdd per block-chunk).
// Then: exact fp32-chain dist per candidate -> atomicMin (fmap(dist)<<32|n)
// = numpy first-index tie-break. EMA epilogue via inverted index.
//
// Candidate-set equivalence: s(m,n) <= thr(m) implies tilemin(m,tile(n)) <=
// s <= thr, so the tile survives and (m,n) is enumerated by score_gather with
// the bit-identical s -> identical candidate set. tlist/flat order is
// irrelevant: downstream is order-independent atomicMin resolution.

typedef _Float16 half8 __attribute__((ext_vector_type(8)));
typedef _Float16 half4 __attribute__((ext_vector_type(4)));
typedef __attribute__((ext_vector_type(4))) float floatx4;

namespace {
constexpr int kN = 32768;
constexpr int kK = 8192;
constexpr int kD = 256;
constexpr int NTIL = kK / 128;     // 64 code tiles
constexpr int JSLOT = 32;          // chunk-slots per tile in score_gather
constexpr int NSEG = 64;
constexpr int SEGCAP = 16384;      // int2 per segment; 64*16384 = 1M entries
constexpr float WWIN = 2.0e-4f;    // containment needs ~8.5e-5; 2.3x margin

// ---- workspace layout (bytes) ----
constexpr size_t OFF_HIST = 0;                                // int K
constexpr size_t OFF_NS   = OFF_HIST + (size_t)kK * 4;        // double
constexpr size_t OFF_SEG  = OFF_NS + 8;                       // uint NSEG
constexpr size_t OFF_TCNT = OFF_SEG + (size_t)NSEG * 4;       // uint NTIL
constexpr size_t ZERO_BYTES = OFF_TCNT + (size_t)NTIL * 4;
constexpr size_t OFF_RKEY = (ZERO_BYTES + 63) & ~(size_t)63;  // ull N, 0xFF
constexpr size_t FF_BYTES = (size_t)kN * 8;
constexpr size_t OFF_SZ   = OFF_RKEY + (size_t)kN * 8;        // float N
constexpr size_t OFF_CW   = OFF_SZ + (size_t)kN * 4;          // float K
constexpr size_t OFF_THR  = OFF_CW + (size_t)kK * 4;          // float N
constexpr size_t OFF_Z16  = OFF_THR + (size_t)kN * 4;         // f16 N*D
constexpr size_t OFF_W16  = OFF_Z16 + (size_t)kN * kD * 2;    // f16 K*D
// tmin (float NTIL*N = 8 MB) dead after append_k; flat (int2 NSEG*SEGCAP =
// 8 MB) live from score_gather on -> UNION the two regions.
constexpr size_t OFF_TMIN = OFF_W16 + (size_t)kK * kD * 2;
constexpr size_t OFF_FLAT = OFF_TMIN;
static_assert((size_t)NSEG * SEGCAP * 8 == (size_t)NTIL * kN * 4,
              "flat must fit exactly in tmin region");
constexpr size_t OFF_TLIST = OFF_TMIN + (size_t)NTIL * kN * 4; // int NTIL*N
constexpr size_t OFF_IDX  = OFF_TLIST + (size_t)NTIL * kN * 4; // int N
constexpr size_t OFF_OFFS = OFF_IDX + (size_t)kN * 4;         // int K
constexpr size_t OFF_CUR  = OFF_OFFS + (size_t)kK * 4;        // int K
constexpr size_t OFF_ROWL = OFF_CUR + (size_t)kK * 4;         // int N
constexpr size_t OFF_PART = OFF_ROWL + (size_t)kN * 4;        // double N
constexpr size_t OFF_PART2 = OFF_PART + (size_t)kN * 8;       // double 64
} // namespace

__device__ __forceinline__ unsigned fmap(float f) {
  unsigned u = __float_as_uint(f);
  return (u & 0x80000000u) ? ~u : (u | 0x80000000u);
}
__device__ __forceinline__ float funmap(unsigned m) {
  unsigned u = (m & 0x80000000u) ? (m & 0x7fffffffu) : ~m;
  return __uint_as_float(u);
}
__device__ __forceinline__ void gload16(const void* g, void* l) {
  __builtin_amdgcn_global_load_lds(
      (const __attribute__((address_space(1))) unsigned int*)g,
      (__attribute__((address_space(3))) unsigned int*)l, 16, 0, 0);
}

// ---------------- numpy AVX512 pairwise sum of squares ----------------
__device__ __forceinline__ float pw_block128_sq(const float* __restrict__ p) {
#pragma clang fp contract(off)
  float u[16];
#pragma unroll
  for (int l = 0; l < 16; ++l) {
    const float x0 = p[l] * p[l];
    const float x1 = p[16 + l] * p[16 + l];
    const float x2 = p[32 + l] * p[32 + l];
    const float x3 = p[48 + l] * p[48 + l];
    const float x4 = p[64 + l] * p[64 + l];
    const float x5 = p[80 + l] * p[80 + l];
    const float x6 = p[96 + l] * p[96 + l];
    const float x7 = p[112 + l] * p[112 + l];
    u[l] = ((x0 + x1) + (x2 + x3)) + ((x4 + x5) + (x6 + x7));
  }
  float t1[8], t2[4], t3[2];
#pragma unroll
  for (int l = 0; l < 8; ++l) t1[l] = u[l] + u[l + 8];
#pragma unroll
  for (int l = 0; l < 4; ++l) t2[l] = t1[l] + t1[l + 4];
#pragma unroll
  for (int l = 0; l < 2; ++l) t3[l] = t2[l] + t2[l + 2];
  return t3[0] + t3[1];
}

// ---------------- fused fp16 convert + numpy-order row sums (z and w) ------
__global__ __launch_bounds__(256) void prep2(const float* __restrict__ z,
                                             const float* __restrict__ w,
                                             _Float16* __restrict__ z16,
                                             _Float16* __restrict__ w16,
                                             float* __restrict__ sz,
                                             float* __restrict__ cw) {
  const bool isz = (blockIdx.x < 1024);
  const int b = isz ? blockIdx.x : blockIdx.x - 1024;
  const int nblocks = isz ? 1024 : 256;
  const int nrows = isz ? kN : kK;
  const float scale = isz ? 1.0f : 16384.0f;
  const float* x = isz ? z : w;
  _Float16* out16 = isz ? z16 : w16;
  float* sums = isz ? sz : cw;

  const int gid = b * 256 + threadIdx.x;
  const int gtot = nblocks * 256;
  const int nf4 = nrows * (kD / 4);
  for (int i = gid; i < nf4; i += gtot) {
    const float4 v = ((const float4*)x)[i];
    half4 h;
    h.x = (_Float16)(v.x * scale);
    h.y = (_Float16)(v.y * scale);
    h.z = (_Float16)(v.z * scale);
    h.w = (_Float16)(v.w * scale);
    ((half4*)out16)[i] = h;
  }
  for (int r = gid; r < nrows; r += gtot) {
    const float* p = x + (size_t)r * kD;
    sums[r] = pw_block128_sq(p) + pw_block128_sq(p + 128);
  }
}

// ---------------- 8-phase MFMA score pass: 256x256 tile, BK=64 -------------
// grid 4096 (128 m-blocks inner x 32 n-blocks), 512 threads (8 waves 2Mx4N).
// Per-wave output 128x64. LDS 128KB double-buffered, XOR-swizzled 16B chunks.
// Staging units per K-tile (2 per-wave loads each, FIFO order U0,U2,U1,U3):
//   U0 = A rows {(r&127)<64}, U1 = A rows {(r&127)>=64},
//   U2 = B rows {(r&63)<32},  U3 = B rows {(r&63)>=32}.
// Phase p consumes quadrant (mhalf=p&1, nhalf=p>>1):
//   ph0:{U0,U2} ph1:{U1,U2} ph2:{U0,U3} ph3:{U1,U3}.
// Issue during tile T (for T+1): ph0->U0, ph1->U2, ph2->U1, ph3->U3.
// Counted waits (per-wave FIFO): kt<3: vmcnt(6) at ph0/ph1/ph2; tail: 4/2/0.
#define SCHED0 __builtin_amdgcn_sched_barrier(0)
#define BAR __builtin_amdgcn_s_barrier()

#define STAGE_A(pa, kt1)                                                 \
  {                                                                      \
    const int q_ = (pa) * 8 + wid;                                       \
    const int r_ = q_ * 8 + (lane >> 3);                                 \
    const int c_ = (lane & 7) ^ (r_ & 7);                                \
    gload16(z16 + (size_t)(m0 + r_) * kD + (kt1) * 64 + c_ * 8,          \
            &As[(kt1) & 1][q_ * 512]);                                   \
  }

#define STAGE_B(h, cc, kt1)                                              \
  {                                                                      \
    const int rb_ = (h) * 32 + (cc) * 128 + (wid >> 2) * 64 + (wid & 3) * 8; \
    const int r_ = rb_ + (lane >> 3);                                    \
    const int c_ = (lane & 7) ^ (r_ & 7);                                \
    gload16(w16 + (size_t)(n0 + r_) * kD + (kt1) * 64 + c_ * 8,          \
            &Bs[(kt1) & 1][rb_ * 64]);                                   \
  }

#define PHASE(cur, mh, nh)                                               \
  {                                                                      \
    half8 af[4][2], bf[2][2];                                            \
    _Pragma("unroll") for (int mt = 0; mt < 4; ++mt) {                   \
      const int row = wr * 128 + (mh) * 64 + mt * 16 + l16;              \
      _Pragma("unroll") for (int kc = 0; kc < 2; ++kc)                   \
        af[mt][kc] = *(const half8*)&As[cur][row * 64 +                  \
                                           (((kc * 4 + quad) ^ (row & 7)) * 8)]; \
    }                                                                    \
    _Pragma("unroll") for (int nt = 0; nt < 2; ++nt) {                   \
      const int row = wc * 64 + (nh) * 32 + nt * 16 + l16;               \
      _Pragma("unroll") for (int kc = 0; kc < 2; ++kc)                   \
        bf[nt][kc] = *(const half8*)&Bs[cur][row * 64 +                  \
                                           (((kc * 4 + quad) ^ (row & 7)) * 8)]; \
    }                                                                    \
    __builtin_amdgcn_s_setprio(1);                                       \
    _Pragma("unroll") for (int kc = 0; kc < 2; ++kc)                     \
      _Pragma("unroll") for (int mt = 0; mt < 4; ++mt)                   \
        _Pragma("unroll") for (int nt = 0; nt < 2; ++nt)                 \
          acc[(mh) * 4 + mt][(nh) * 2 + nt] =                            \
              __builtin_amdgcn_mfma_f32_16x16x32_f16(                    \
                  af[mt][kc], bf[nt][kc],                                \
                  acc[(mh) * 4 + mt][(nh) * 2 + nt], 0, 0, 0);           \
    __builtin_amdgcn_s_setprio(0);                                       \
  }

__global__ __launch_bounds__(512, 2) void score_min(
    const _Float16* __restrict__ z16, const _Float16* __restrict__ w16,
    const float* __restrict__ cw, float* __restrict__ tmin) {
  __shared__ _Float16 As[2][256 * 64];  // 64 KB
  __shared__ _Float16 Bs[2][256 * 64];  // 64 KB

  const int tid = threadIdx.x;
  const int wid = tid >> 6;
  const int lane = tid & 63;
  const int l16 = lane & 15;
  const int quad = lane >> 4;
  const int wr = wid >> 2;   // 0..1 (row half)
  const int wc = wid & 3;    // 0..3 (col quarter)
  const int blkM = blockIdx.x & 127;
  const int blkN = blockIdx.x >> 7;
  const int m0 = blkM * 256;
  const int n0 = blkN * 256;

  float cwv[4];
#pragma unroll
  for (int j = 0; j < 4; ++j)
    cwv[j] = cw[n0 + wc * 64 + j * 16 + l16];

  floatx4 acc[8][4];
#pragma unroll
  for (int a = 0; a < 8; ++a)
#pragma unroll
    for (int b = 0; b < 4; ++b) acc[a][b] = (floatx4){0.f, 0.f, 0.f, 0.f};

  // prologue: tile 0, FIFO order U0, U2, U1, U3
  STAGE_A(0, 0); STAGE_A(2, 0);
  STAGE_B(0, 0, 0); STAGE_B(0, 1, 0);
  STAGE_A(1, 0); STAGE_A(3, 0);
  STAGE_B(1, 0, 0); STAGE_B(1, 1, 0);

#pragma unroll
  for (int kt = 0; kt < 4; ++kt) {
    const int cur = kt & 1;
    // ---- phase 0: quadrant (0,0); stage U0(next) ----
    if (kt < 3) { STAGE_A(0, kt + 1); STAGE_A(2, kt + 1); }
    if (kt < 3) { asm volatile("s_waitcnt vmcnt(6)" ::: "memory"); }
    else        { asm volatile("s_waitcnt vmcnt(4)" ::: "memory"); }
    SCHED0; BAR; SCHED0;
    PHASE(cur, 0, 0);
    BAR;
    // ---- phase 1: quadrant (1,0); stage U2(next) ----
    if (kt < 3) { STAGE_B(0, 0, kt + 1); STAGE_B(0, 1, kt + 1); }
    if (kt < 3) { asm volatile("s_waitcnt vmcnt(6)" ::: "memory"); }
    else        { asm volatile("s_waitcnt vmcnt(2)" ::: "memory"); }
    SCHED0; BAR; SCHED0;
    PHASE(cur, 1, 0);
    BAR;
    // ---- phase 2: quadrant (0,1); stage U1(next) ----
    if (kt < 3) { STAGE_A(1, kt + 1); STAGE_A(3, kt + 1); }
    if (kt < 3) { asm volatile("s_waitcnt vmcnt(6)" ::: "memory"); }
    else        { asm volatile("s_waitcnt vmcnt(0)" ::: "memory"); }
    SCHED0; BAR; SCHED0;
    PHASE(cur, 0, 1);
    BAR;
    // ---- phase 3: quadrant (1,1); stage U3(next) ----
    if (kt < 3) { STAGE_B(1, 0, kt + 1); STAGE_B(1, 1, kt + 1); }
    SCHED0; BAR; SCHED0;
    PHASE(cur, 1, 1);
    BAR;  // all reads of buf[cur] done before next tile stages into it
  }

  // ---- epilogue: per-wave 64-col row-mins -> LDS -> 128-col tile mins ----
  // (min is exact/order-free; grouping matches the old kernel bit-for-bit)
  float* pm = (float*)&As[0][0];  // 8 warps x 128 rows = 4 KB scratch
#pragma unroll
  for (int mt = 0; mt < 8; ++mt) {
#pragma unroll
    for (int r = 0; r < 4; ++r) {
      float mn = 3.4e38f;
#pragma unroll
      for (int j = 0; j < 4; ++j)
        mn = fminf(mn, fmaf(acc[mt][j][r], -1.220703125e-4f, cwv[j]));
#pragma unroll
      for (int off = 1; off < 16; off <<= 1)
        mn = fminf(mn, __shfl_xor(mn, off));
      if (l16 == 0) pm[wid * 128 + mt * 16 + quad * 4 + r] = mn;
    }
  }
  __syncthreads();
  {
    const int tile = tid >> 8;        // 0..1 (128-code tmin tile within block)
    const int row = tid & 255;        // 0..255
    const int wrr = row >> 7;
    const int r7 = row & 127;
    const float v = fminf(pm[(wrr * 4 + tile * 2 + 0) * 128 + r7],
                          pm[(wrr * 4 + tile * 2 + 1) * 128 + r7]);
    tmin[(size_t)(blkN * 2 + tile) * kN + m0 + row] = v;
  }
}

// ---------------- row thresholds (no atomics) ------------------------------
__global__ __launch_bounds__(256) void rowmin_k(const float* __restrict__ tmin,
                                                float* __restrict__ thrv) {
  const int tid = threadIdx.x;
  const int w = tid >> 6;            // tile quarter 0..3
  const int lane = tid & 63;
  const int m = blockIdx.x * 64 + lane;

  float v[16];
#pragma unroll
  for (int i = 0; i < 16; ++i)
    v[i] = tmin[(size_t)(w * 16 + i) * kN + m];

  float mn = fminf(v[0], v[1]);
#pragma unroll
  for (int i = 2; i < 16; ++i) mn = fminf(mn, v[i]);

  __shared__ float red[4][64];
  red[w][lane] = mn;
  __syncthreads();
  if (w == 0)
    thrv[m] = fminf(fminf(red[0][lane], red[1][lane]),
                    fminf(red[2][lane], red[3][lane])) + WWIN;
}

// ---------------- survivor-list build (one atomic per block) ---------------
__global__ __launch_bounds__(256) void append_k(const float* __restrict__ tmin,
                                                const float* __restrict__ thrv,
                                                unsigned* __restrict__ tcnt,
                                                int* __restrict__ tlist) {
  const int t = blockIdx.x >> 3;
  const int slice = blockIdx.x & 7;
  const int tid = threadIdx.x;
  const int m0 = slice * (kN / 8);
  const float* tm = tmin + (size_t)t * kN;

  unsigned okbits = 0;
#pragma unroll
  for (int it = 0; it < 16; ++it) {
    const int m = m0 + it * 256 + tid;
    if (tm[m] <= thrv[m]) okbits |= (1u << it);
  }
  const int cnt = __popc(okbits);

  __shared__ int itmp[256];
  __shared__ int sbase;
  itmp[tid] = cnt;
  __syncthreads();
  for (int off = 1; off < 256; off <<= 1) {
    const int add = (tid >= off) ? itmp[tid - off] : 0;
    __syncthreads();
    itmp[tid] += add;
    __syncthreads();
  }
  if (tid == 255) sbase = (int)atomicAdd(&tcnt[t], (unsigned)itmp[255]);
  __syncthreads();

  int pos = sbase + itmp[tid] - cnt;
  int* tl = tlist + (size_t)t * kN;
#pragma unroll
  for (int it = 0; it < 16; ++it)
    if ((okbits >> it) & 1u) tl[pos++] = m0 + it * 256 + tid;
}

// ---------------- gathered-row MFMA re-score over surviving pairs ----------
__global__ __launch_bounds__(256, 4) void score_gather(
    const _Float16* __restrict__ z16, const _Float16* __restrict__ w16,
    const float* __restrict__ cw, const float* __restrict__ thrv,
    const unsigned* __restrict__ tcnt, const int* __restrict__ tlist,
    unsigned* __restrict__ segcnt, int2* __restrict__ flat) {
  __shared__ _Float16 Asg[128 * 64];
  __shared__ _Float16 Bsg[128 * 64];
  __shared__ int itmp[256];
  __shared__ int sbase;

  const int tid = threadIdx.x;
  const int wid = tid >> 6;
  const int lane = tid & 63;
  const int l16 = lane & 15;
  const int quad = lane >> 4;
  const int t = blockIdx.x & (NTIL - 1);
  const int j0 = blockIdx.x >> 6;  // 0..JSLOT-1
  const int n0 = t * 128;
  const int rowbase = (wid >> 1) * 64;
  const int colbase = (wid & 1) * 64;
  const int ct = (int)tcnt[t];
  if (j0 * 128 >= ct) return;
  const int bucket = blockIdx.x & (NSEG - 1);  // spread skewed tiles
  const int* rlist = tlist + (size_t)t * kN;

  float cwv[4];
#pragma unroll
  for (int nt = 0; nt < 4; ++nt)
    cwv[nt] = cw[n0 + colbase + nt * 16 + l16];

  for (int chunk = j0; chunk * 128 < ct; chunk += JSLOT) {
    const int base = chunk * 128;
    floatx4 acc[4][4];
#pragma unroll
    for (int a = 0; a < 4; ++a)
#pragma unroll
      for (int b = 0; b < 4; ++b) acc[a][b] = (floatx4){0.f, 0.f, 0.f, 0.f};

    for (int kt = 0; kt < 4; ++kt) {
      const int d0 = kt * 64;
      __syncthreads();
#pragma unroll
      for (int p = 0; p < 4; ++p) {  // A: 128 gathered rows x 64 d
        const int q = p * 4 + wid;
        const int r = q * 8 + (lane >> 3);
        const int c = (lane & 7) ^ (r & 7);
        int gi = base + r;
        if (gi >= ct) gi = base;  // pad with dup of first row in chunk
        gload16(z16 + (size_t)rlist[gi] * kD + d0 + c * 8, &Asg[q * 512]);
      }
#pragma unroll
      for (int p = 0; p < 4; ++p) {  // B: 128 codes x 64 d
        const int q = p * 4 + wid;
        const int r = q * 8 + (lane >> 3);
        const int c = (lane & 7) ^ (r & 7);
        gload16(w16 + (size_t)(n0 + r) * kD + d0 + c * 8, &Bsg[q * 512]);
      }
      __syncthreads();
#pragma unroll
      for (int kc = 0; kc < 2; ++kc) {
        half8 af[4], bfr[4];
#pragma unroll
        for (int mt = 0; mt < 4; ++mt) {
          const int row = rowbase + mt * 16 + l16;
          const int j = (kc * 4 + quad) ^ (row & 7);
          af[mt] = *(const half8*)&Asg[row * 64 + j * 8];
        }
#pragma unroll
        for (int nt = 0; nt < 4; ++nt) {
          const int row = colbase + nt * 16 + l16;
          const int j = (kc * 4 + quad) ^ (row & 7);
          bfr[nt] = *(const half8*)&Bsg[row * 64 + j * 8];
        }
#pragma unroll
        for (int mt = 0; mt < 4; ++mt)
#pragma unroll
          for (int nt = 0; nt < 4; ++nt)
            acc[mt][nt] = __builtin_amdgcn_mfma_f32_16x16x32_f16(
                af[mt], bfr[nt], acc[mt][nt], 0, 0, 0);
      }
    }

    // ---- block-aggregated candidate insert ----
    unsigned long long cmask = 0ull;
    int ccnt = 0;
    int mrow[16];
#pragma unroll
    for (int mt = 0; mt < 4; ++mt) {
#pragma unroll
      for (int r = 0; r < 4; ++r) {
        int gi = base + rowbase + mt * 16 + quad * 4 + r;
        const bool vrow = (gi < ct);
        if (!vrow) gi = base;
        const int m = rlist[gi];
        mrow[mt * 4 + r] = m;
        const float th = thrv[m];
#pragma unroll
        for (int nt = 0; nt < 4; ++nt) {
          const float s = fmaf(acc[mt][nt][r], -1.220703125e-4f, cwv[nt]);
          if (vrow && s <= th) {
            cmask |= 1ull << (mt * 16 + r * 4 + nt);
            ++ccnt;
          }
        }
      }
    }
    __syncthreads();  // itmp reuse: prior-chunk reads complete
    itmp[tid] = ccnt;
    __syncthreads();
    for (int off = 1; off < 256; off <<= 1) {
      const int add = (tid >= off) ? itmp[tid - off] : 0;
      __syncthreads();
      itmp[tid] += add;
      __syncthreads();
    }
    if (tid == 255)
      sbase = itmp[255] ? (int)atomicAdd(&segcnt[bucket], (unsigned)itmp[255])
                        : 0;
    __syncthreads();
    if (cmask) {
      int pos = sbase + itmp[tid] - ccnt;
#pragma unroll
      for (int mt = 0; mt < 4; ++mt) {
#pragma unroll
        for (int r = 0; r < 4; ++r) {
          const int m = mrow[mt * 4 + r];
#pragma unroll
          for (int nt = 0; nt < 4; ++nt) {
            if ((cmask >> (mt * 16 + r * 4 + nt)) & 1ull) {
              if ((unsigned)pos < (unsigned)SEGCAP)
                flat[(size_t)bucket * SEGCAP + pos] =
                    make_int2(m, n0 + colbase + nt * 16 + l16);
              ++pos;
            }
          }
        }
      }
    }
  }
}

// ---------------- exact fp32-chain dist per candidate (segmented) ----------
__global__ __launch_bounds__(256) void exact_kernel(
    const float* __restrict__ z, const float* __restrict__ emb,
    const float* __restrict__ sz, const float* __restrict__ cw,
    const int2* __restrict__ flat, const unsigned* __restrict__ segcnt,
    unsigned long long* __restrict__ rkey) {
#pragma clang fp contract(off)
  const int i = blockIdx.x * 256 + threadIdx.x;
  const int seg = i >> 14;           // SEGCAP = 16384
  const int off = i & (SEGCAP - 1);
  unsigned cnt = segcnt[seg];
  if (cnt > (unsigned)SEGCAP) cnt = SEGCAP;
  if (off >= (int)cnt) return;
  const int2 c = flat[(size_t)seg * SEGCAP + off];
  const int m = c.x, n = c.y;
  const float* zrow = z + (size_t)m * kD;
  const float* wrow = emb + (size_t)n * kD;
  float a = 0.f;
  for (int d4 = 0; d4 < kD; d4 += 4) {
    const float4 zv = *(const float4*)&zrow[d4];
    const float4 wv = *(const float4*)&wrow[d4];
    a = __builtin_fmaf(zv.x, wv.x, a);
    a = __builtin_fmaf(zv.y, wv.y, a);
    a = __builtin_fmaf(zv.z, wv.z, a);
    a = __builtin_fmaf(zv.w, wv.w, a);
  }
  const float u = sz[m] - 2.0f * a;
  const float dist = u + cw[n];
  const unsigned long long key =
      ((unsigned long long)fmap(dist) << 32) | (unsigned)n;
  atomicMin(&rkey[m], key);  // equal dist -> lower n (numpy first-index)
}

// ---------------- finalize idx + hist + z_q_st + commit partials ----------
__global__ __launch_bounds__(256) void finalize_zq(
    const unsigned long long* __restrict__ rkey, const float* __restrict__ z,
    const float* __restrict__ emb, int* __restrict__ idxg,
    float* __restrict__ out_idx, int* __restrict__ hist,
    float* __restrict__ out_zq, double* __restrict__ part) {
#pragma clang fp contract(off)
  const int n = blockIdx.x;
  const int d = threadIdx.x;
  const int k = (int)(rkey[n] & 0xffffffffu);
  if (d == 0) {
    idxg[n] = k;
    out_idx[n] = (float)k;
    atomicAdd(&hist[k], 1);
  }
  const float zv = z[(size_t)n * kD + d];
  const float q = emb[(size_t)k * kD + d];
  out_zq[(size_t)n * kD + d] = zv + (q - zv);
  const float diff = zv - q;
  double v = (double)diff * (double)diff;
#pragma unroll
  for (int m = 32; m; m >>= 1) v += __shfl_xor(v, m);
  __shared__ double p4[4];
  if ((d & 63) == 0) p4[d >> 6] = v;
  __syncthreads();
  if (d == 0) part[n] = p4[0] + p4[1] + p4[2] + p4[3];
}

// ---------------- pre-reduce commit partials: 32768 -> 64 ------------------
__global__ __launch_bounds__(256) void reduce_part(
    const double* __restrict__ part, double* __restrict__ part2) {
#pragma clang fp contract(off)
  const int b = blockIdx.x;  // 64
  const int tid = threadIdx.x;
  double s = part[b * 512 + tid] + part[b * 512 + 256 + tid];
#pragma unroll
  for (int m = 32; m; m >>= 1) s += __shfl_xor(s, m);
  __shared__ double p4[4];
  if ((tid & 63) == 0) p4[tid >> 6] = s;
  __syncthreads();
  if (tid == 0) part2[b] = p4[0] + p4[1] + p4[2] + p4[3];
}

// ---------------- single-block: commit reduce + newcount + nsum + prefix ----
__global__ __launch_bounds__(256) void mid_k(
    const double* __restrict__ part2, float* __restrict__ out_com,
    const int* __restrict__ hist, const float* __restrict__ ec,
    float* __restrict__ out_cnt, double* __restrict__ nsum,
    int* __restrict__ offs, int* __restrict__ cursor) {
#pragma clang fp contract(off)
  const int t = threadIdx.x;
  __shared__ double dtmp[4];
  __shared__ int itmp[256];

  double s = (t < 64) ? part2[t] : 0.0;
#pragma unroll
  for (int m = 32; m; m >>= 1) s += __shfl_xor(s, m);
  if ((t & 63) == 0) dtmp[t >> 6] = s;
  __syncthreads();
  if (t == 0)
    out_com[0] = (float)(0.25 * (dtmp[0] + dtmp[1] + dtmp[2] + dtmp[3]) /
                         (double)((size_t)kN * kD));
  __syncthreads();

  const int base = t * 32;
  double ns = 0.0;
  int run = 0;
  for (int c = 0; c < 32; ++c) {
    const int k = base + c;
    const float nc = 0.99f * ec[k] + 0.01f * (float)hist[k];
    out_cnt[k] = nc;
    ns += (double)nc;
    run += hist[k];
  }
  itmp[t] = run;
  __syncthreads();
  for (int off = 1; off < 256; off <<= 1) {
    const int add = (t >= off) ? itmp[t - off] : 0;
    __syncthreads();
    itmp[t] += add;
    __syncthreads();
  }
  int run2 = itmp[t] - run;
  for (int c = 0; c < 32; ++c) {
    const int k = base + c;
    offs[k] = run2;
    cursor[k] = run2;
    run2 += hist[k];
  }
#pragma unroll
  for (int m = 32; m; m >>= 1) ns += __shfl_xor(ns, m);
  if ((t & 63) == 0) dtmp[t >> 6] = ns;
  __syncthreads();
  if (t == 0) *nsum = dtmp[0] + dtmp[1] + dtmp[2] + dtmp[3];
}

// ---------------- scatter rows into per-code lists ----------------
__global__ __launch_bounds__(256) void scatter_k(const int* __restrict__ idxg,
                                                 int* __restrict__ cursor,
                                                 int* __restrict__ rowlist) {
  const int r = blockIdx.x * 256 + threadIdx.x;
  const int k = idxg[r];
  const int pos = atomicAdd(&cursor[k], 1);
  rowlist[pos] = r;
}

// ---------------- new_avg + new_embed via gathered row sums ----------------
__global__ __launch_bounds__(256) void newavg_k(
    const float* __restrict__ z, const float* __restrict__ ea,
    const int* __restrict__ hist, const int* __restrict__ offs,
    const int* __restrict__ rowlist, const float* __restrict__ out_cnt,
    const double* __restrict__ nsum, float* __restrict__ out_emb,
    float* __restrict__ out_avg) {
#pragma clang fp contract(off)
  const int k = blockIdx.x;
  const int d = threadIdx.x;
  const int c = hist[k];
  const int off = offs[k];
  float s = 0.f;
  for (int j = 0; j < c; ++j)
    s += z[(size_t)rowlist[off + j] * kD + d];
  const size_t o = (size_t)k * kD + d;
  const float na = 0.99f * ea[o] + 0.01f * s;
  out_avg[o] = na;
  const float nf = (float)(*nsum);
  const float nc = out_cnt[k];
  const float keps = 0.08192f;  // fl(K * EPS)
  const float cs = (nc + 1e-5f) / (nf + keps) * nf;
  out_emb[o] = na / cs;
}

extern "C" void kernel_launch(void* const* d_in, const int* in_sizes, int n_in,
                              void* d_out, int out_size, void* d_ws, size_t ws_size,
                              hipStream_t stream) {
  const float* z_e       = (const float*)d_in[0];
  const float* embedding = (const float*)d_in[1];
  const float* ema_count = (const float*)d_in[2];
  const float* ema_avg   = (const float*)d_in[3];

  char* ws = (char*)d_ws;
  int*    hist   = (int*)(ws + OFF_HIST);
  double* nsum   = (double*)(ws + OFF_NS);
  unsigned* segcnt = (unsigned*)(ws + OFF_SEG);
  unsigned* tcnt = (unsigned*)(ws + OFF_TCNT);
  unsigned long long* rkey = (unsigned long long*)(ws + OFF_RKEY);
  float*  sz     = (float*)(ws + OFF_SZ);
  float*  cw     = (float*)(ws + OFF_CW);
  float*  thrv   = (float*)(ws + OFF_THR);
  _Float16* z16  = (_Float16*)(ws + OFF_Z16);
  _Float16* w16  = (_Float16*)(ws + OFF_W16);
  float*  tmin   = (float*)(ws + OFF_TMIN);
  int2*   flat   = (int2*)(ws + OFF_FLAT);
  int*    tlist  = (int*)(ws + OFF_TLIST);
  int*    idxg   = (int*)(ws + OFF_IDX);
  int*    offs   = (int*)(ws + OFF_OFFS);
  int*    cursor = (int*)(ws + OFF_CUR);
  int*    rowlist= (int*)(ws + OFF_ROWL);
  double* part   = (double*)(ws + OFF_PART);
  double* part2  = (double*)(ws + OFF_PART2);

  float* out_zq  = (float*)d_out;
  float* out_com = out_zq + (size_t)kN * kD;
  float* out_idx = out_com + 1;
  float* out_emb = out_idx + kN;
  float* out_cnt = out_emb + (size_t)kK * kD;
  float* out_avg = out_cnt + kK;

  hipMemsetAsync(ws, 0, ZERO_BYTES, stream);
  hipMemsetAsync(ws + OFF_RKEY, 0xFF, FF_BYTES, stream);

  prep2<<<1280, 256, 0, stream>>>(z_e, embedding, z16, w16, sz, cw);
  score_min<<<(kN / 256) * (kK / 256), 512, 0, stream>>>(z16, w16, cw, tmin);
  rowmin_k<<<kN / 64, 256, 0, stream>>>(tmin, thrv);
  append_k<<<NTIL * 8, 256, 0, stream>>>(tmin, thrv, tcnt, tlist);
  score_gather<<<NTIL * JSLOT, 256, 0, stream>>>(z16, w16, cw, thrv, tcnt,
                                                 tlist, segcnt, flat);
  exact_kernel<<<(NSEG * SEGCAP) / 256, 256, 0, stream>>>(
      z_e, embedding, sz, cw, flat, segcnt, rkey);
  finalize_zq<<<kN, 256, 0, stream>>>(rkey, z_e, embedding, idxg, out_idx,
                                      hist, out_zq, part);
  reduce_part<<<64, 256, 0, stream>>>(part, part2);
  mid_k<<<1, 256, 0, stream>>>(part2, out_com, hist, ema_count, out_cnt, nsum,
                               offs, cursor);
  scatter_k<<<kN / 256, 256, 0, stream>>>(idxg, cursor, rowlist);
  newavg_k<<<kK, 256, 0, stream>>>(z_e, ema_avg, hist, offs, rowlist, out_cnt,
                                   nsum, out_emb, out_avg);
}

// Round 7
// 591.848 us; speedup vs baseline: 1.0922x; 1.0922x over previous
//
#include <hip/hip_runtime.h>

// VectorQuantizerEMA  N=32768 K=8192 D=256  fp32
// Outputs: z_q_st[N*D], commitment[1], idx[N], new_embed[K*D], new_count[K], new_avg[K*D]
//
// Single full fp16 MFMA score GEMM (z16 * (w*2^14)16):
//   score_min: 128x128 tile, BK=64, 4 waves, 2-barrier K-loop (proven r5
//              structure; the r6 8-phase 256^2 port REGRESSED 197->276us:
//              1 block/CU + only 4 K-tiles -> pipeline fill/drain dominated).
//              pairmin scratch ALIASED onto As (dead after K-loop) -> LDS
//              32768 B -> 5 blocks/CU (was 4 at 33792): +25% resident waves
//              to hide the barrier-drain stall. Per-(row,128-code-tile) min
//              -> tmin[ntile][row] (plain stores, unique writer).
//   rowmin_k:  thr[m] = min over 64 tile-mins + WWIN.
//   append_k:  512 blocks: 16-bit survivor masks, block prefix-scan, ONE
//              global atomicAdd per block.
//   score_gather: gathered-row 128x128 MFMA re-score ONLY for surviving pairs
//              (same per-fragment K-chain -> bit-identical scores);
//              block-aggregated insert (one atomicAdd per block-chunk).
// Then: exact fp32-chain dist per candidate -> atomicMin (fmap(dist)<<32|n)
// = numpy first-index tie-break. EMA epilogue via inverted index.
//
// Candidate-set equivalence: s(m,n) <= thr(m) implies tilemin(m,tile(n)) <=
// s <= thr, so the tile survives and (m,n) is enumerated by score_gather with
// the bit-identical s -> identical candidate set. tlist/flat order is
// irrelevant: downstream is order-independent atomicMin resolution.

typedef _Float16 half8 __attribute__((ext_vector_type(8)));
typedef _Float16 half4 __attribute__((ext_vector_type(4)));
typedef __attribute__((ext_vector_type(4))) float floatx4;

namespace {
constexpr int kN = 32768;
constexpr int kK = 8192;
constexpr int kD = 256;
constexpr int NTIL = kK / 128;     // 64 code tiles
constexpr int JSLOT = 32;          // chunk-slots per tile in score_gather
constexpr int NSEG = 64;
constexpr int SEGCAP = 16384;      // int2 per segment; 64*16384 = 1M entries
constexpr float WWIN = 2.0e-4f;    // containment needs ~8.5e-5; 2.3x margin

// ---- workspace layout (bytes) ----
constexpr size_t OFF_HIST = 0;                                // int K
constexpr size_t OFF_NS   = OFF_HIST + (size_t)kK * 4;        // double
constexpr size_t OFF_SEG  = OFF_NS + 8;                       // uint NSEG
constexpr size_t OFF_TCNT = OFF_SEG + (size_t)NSEG * 4;       // uint NTIL
constexpr size_t ZERO_BYTES = OFF_TCNT + (size_t)NTIL * 4;
constexpr size_t OFF_RKEY = (ZERO_BYTES + 63) & ~(size_t)63;  // ull N, 0xFF
constexpr size_t FF_BYTES = (size_t)kN * 8;
constexpr size_t OFF_SZ   = OFF_RKEY + (size_t)kN * 8;        // float N
constexpr size_t OFF_CW   = OFF_SZ + (size_t)kN * 4;          // float K
constexpr size_t OFF_THR  = OFF_CW + (size_t)kK * 4;          // float N
constexpr size_t OFF_Z16  = OFF_THR + (size_t)kN * 4;         // f16 N*D
constexpr size_t OFF_W16  = OFF_Z16 + (size_t)kN * kD * 2;    // f16 K*D
// tmin (float NTIL*N = 8 MB) dead after append_k; flat (int2 NSEG*SEGCAP =
// 8 MB) live from score_gather on -> UNION the two regions.
constexpr size_t OFF_TMIN = OFF_W16 + (size_t)kK * kD * 2;
constexpr size_t OFF_FLAT = OFF_TMIN;
static_assert((size_t)NSEG * SEGCAP * 8 == (size_t)NTIL * kN * 4,
              "flat must fit exactly in tmin region");
constexpr size_t OFF_TLIST = OFF_TMIN + (size_t)NTIL * kN * 4; // int NTIL*N
constexpr size_t OFF_IDX  = OFF_TLIST + (size_t)NTIL * kN * 4; // int N
constexpr size_t OFF_OFFS = OFF_IDX + (size_t)kN * 4;         // int K
constexpr size_t OFF_CUR  = OFF_OFFS + (size_t)kK * 4;        // int K
constexpr size_t OFF_ROWL = OFF_CUR + (size_t)kK * 4;         // int N
constexpr size_t OFF_PART = OFF_ROWL + (size_t)kN * 4;        // double N
constexpr size_t OFF_PART2 = OFF_PART + (size_t)kN * 8;       // double 64
} // namespace

__device__ __forceinline__ unsigned fmap(float f) {
  unsigned u = __float_as_uint(f);
  return (u & 0x80000000u) ? ~u : (u | 0x80000000u);
}
__device__ __forceinline__ float funmap(unsigned m) {
  unsigned u = (m & 0x80000000u) ? (m & 0x7fffffffu) : ~m;
  return __uint_as_float(u);
}
__device__ __forceinline__ void gload16(const void* g, void* l) {
  __builtin_amdgcn_global_load_lds(
      (const __attribute__((address_space(1))) unsigned int*)g,
      (__attribute__((address_space(3))) unsigned int*)l, 16, 0, 0);
}

// ---------------- numpy AVX512 pairwise sum of squares ----------------
__device__ __forceinline__ float pw_block128_sq(const float* __restrict__ p) {
#pragma clang fp contract(off)
  float u[16];
#pragma unroll
  for (int l = 0; l < 16; ++l) {
    const float x0 = p[l] * p[l];
    const float x1 = p[16 + l] * p[16 + l];
    const float x2 = p[32 + l] * p[32 + l];
    const float x3 = p[48 + l] * p[48 + l];
    const float x4 = p[64 + l] * p[64 + l];
    const float x5 = p[80 + l] * p[80 + l];
    const float x6 = p[96 + l] * p[96 + l];
    const float x7 = p[112 + l] * p[112 + l];
    u[l] = ((x0 + x1) + (x2 + x3)) + ((x4 + x5) + (x6 + x7));
  }
  float t1[8], t2[4], t3[2];
#pragma unroll
  for (int l = 0; l < 8; ++l) t1[l] = u[l] + u[l + 8];
#pragma unroll
  for (int l = 0; l < 4; ++l) t2[l] = t1[l] + t1[l + 4];
#pragma unroll
  for (int l = 0; l < 2; ++l) t3[l] = t2[l] + t2[l + 2];
  return t3[0] + t3[1];
}

// ---------------- fused fp16 convert + numpy-order row sums (z and w) ------
__global__ __launch_bounds__(256) void prep2(const float* __restrict__ z,
                                             const float* __restrict__ w,
                                             _Float16* __restrict__ z16,
                                             _Float16* __restrict__ w16,
                                             float* __restrict__ sz,
                                             float* __restrict__ cw) {
  const bool isz = (blockIdx.x < 1024);
  const int b = isz ? blockIdx.x : blockIdx.x - 1024;
  const int nblocks = isz ? 1024 : 256;
  const int nrows = isz ? kN : kK;
  const float scale = isz ? 1.0f : 16384.0f;
  const float* x = isz ? z : w;
  _Float16* out16 = isz ? z16 : w16;
  float* sums = isz ? sz : cw;

  const int gid = b * 256 + threadIdx.x;
  const int gtot = nblocks * 256;
  const int nf4 = nrows * (kD / 4);
  for (int i = gid; i < nf4; i += gtot) {
    const float4 v = ((const float4*)x)[i];
    half4 h;
    h.x = (_Float16)(v.x * scale);
    h.y = (_Float16)(v.y * scale);
    h.z = (_Float16)(v.z * scale);
    h.w = (_Float16)(v.w * scale);
    ((half4*)out16)[i] = h;
  }
  for (int r = gid; r < nrows; r += gtot) {
    const float* p = x + (size_t)r * kD;
    sums[r] = pw_block128_sq(p) + pw_block128_sq(p + 128);
  }
}

// ---------------- MFMA score pass: 128x128 tile, BK=64 ---------------------
// grid 16384, mtile INNER (blockIdx&255); per-(row, ntile) block-min written
// to tmin[ntile * kN + row] (unique writer, coalesced, no atomics).
// LDS exactly 32 KB (pairmin aliased onto As) -> 5 blocks/CU.
__global__ __launch_bounds__(256, 4) void score_min(
    const _Float16* __restrict__ z16, const _Float16* __restrict__ w16,
    const float* __restrict__ cw, float* __restrict__ tmin) {
  __shared__ _Float16 As[128 * 64];  // 16 KB, XOR-swizzled 16B chunks (8/row)
  __shared__ _Float16 Bs[128 * 64];  // 16 KB
  unsigned* pairmin = (unsigned*)As;  // 1 KB alias; As dead after K-loop

  const int tid = threadIdx.x;
  const int wid = tid >> 6;
  const int lane = tid & 63;
  const int l16 = lane & 15;
  const int quad = lane >> 4;
  const int m0 = (blockIdx.x & 255) * 128;
  const int nt0 = blockIdx.x >> 8;
  const int n0 = nt0 * 128;
  const int rowbase = (wid >> 1) * 64;
  const int colbase = (wid & 1) * 64;

  floatx4 acc[4][4];
#pragma unroll
  for (int a = 0; a < 4; ++a)
#pragma unroll
    for (int b = 0; b < 4; ++b) acc[a][b] = (floatx4){0.f, 0.f, 0.f, 0.f};

  for (int kt = 0; kt < 4; ++kt) {
    const int d0 = kt * 64;
    __syncthreads();  // prior-iter LDS reads complete before overwrite
#pragma unroll
    for (int p = 0; p < 4; ++p) {  // A: 128 rows x 64 d
      const int q = p * 4 + wid;
      const int r = q * 8 + (lane >> 3);
      const int c = (lane & 7) ^ (r & 7);
      gload16(z16 + (size_t)(m0 + r) * kD + d0 + c * 8, &As[q * 512]);
    }
#pragma unroll
    for (int p = 0; p < 4; ++p) {  // B: 128 codes x 64 d
      const int q = p * 4 + wid;
      const int r = q * 8 + (lane >> 3);
      const int c = (lane & 7) ^ (r & 7);
      gload16(w16 + (size_t)(n0 + r) * kD + d0 + c * 8, &Bs[q * 512]);
    }
    __syncthreads();  // drain staging
#pragma unroll
    for (int kc = 0; kc < 2; ++kc) {
      half8 af[4], bfr[4];
#pragma unroll
      for (int mt = 0; mt < 4; ++mt) {
        const int row = rowbase + mt * 16 + l16;
        const int j = (kc * 4 + quad) ^ (row & 7);
        af[mt] = *(const half8*)&As[row * 64 + j * 8];
      }
#pragma unroll
      for (int nt = 0; nt < 4; ++nt) {
        const int row = colbase + nt * 16 + l16;
        const int j = (kc * 4 + quad) ^ (row & 7);
        bfr[nt] = *(const half8*)&Bs[row * 64 + j * 8];
      }
#pragma unroll
      for (int mt = 0; mt < 4; ++mt)
#pragma unroll
        for (int nt = 0; nt < 4; ++nt)
          acc[mt][nt] = __builtin_amdgcn_mfma_f32_16x16x32_f16(
              af[mt], bfr[nt], acc[mt][nt], 0, 0, 0);
    }
  }
  __syncthreads();  // all waves done reading As before pairmin alias-write

  // ---- scores: w scaled by 2^14 -> -2*2^-14 = -2^-13 exactly ----
  float cwv[4];
#pragma unroll
  for (int nt = 0; nt < 4; ++nt)
    cwv[nt] = cw[n0 + colbase + nt * 16 + l16];

  // block row-min over this block's 128 codes -> tmin[nt0][row]
#pragma unroll
  for (int mt = 0; mt < 4; ++mt)
#pragma unroll
    for (int r = 0; r < 4; ++r) {
      float mn = 3.4e38f;
#pragma unroll
      for (int nt = 0; nt < 4; ++nt)
        mn = fminf(mn, fmaf(acc[mt][nt][r], -1.220703125e-4f, cwv[nt]));
#pragma unroll
      for (int off = 1; off < 16; off <<= 1)
        mn = fminf(mn, __shfl_xor(mn, off));
      if (l16 == 0) pairmin[wid * 64 + mt * 16 + quad * 4 + r] = fmap(mn);
    }
  __syncthreads();
  if ((wid & 1) == 0) {
    const unsigned v =
        min(pairmin[wid * 64 + lane], pairmin[(wid + 1) * 64 + lane]);
    tmin[(size_t)nt0 * kN + m0 + rowbase + lane] = funmap(v);
  }
}

// ---------------- row thresholds (no atomics) ------------------------------
__global__ __launch_bounds__(256) void rowmin_k(const float* __restrict__ tmin,
                                                float* __restrict__ thrv) {
  const int tid = threadIdx.x;
  const int w = tid >> 6;            // tile quarter 0..3
  const int lane = tid & 63;
  const int m = blockIdx.x * 64 + lane;

  float v[16];
#pragma unroll
  for (int i = 0; i < 16; ++i)
    v[i] = tmin[(size_t)(w * 16 + i) * kN + m];

  float mn = fminf(v[0], v[1]);
#pragma unroll
  for (int i = 2; i < 16; ++i) mn = fminf(mn, v[i]);

  __shared__ float red[4][64];
  red[w][lane] = mn;
  __syncthreads();
  if (w == 0)
    thrv[m] = fminf(fminf(red[0][lane], red[1][lane]),
                    fminf(red[2][lane], red[3][lane])) + WWIN;
}

// ---------------- survivor-list build (one atomic per block) ---------------
__global__ __launch_bounds__(256) void append_k(const float* __restrict__ tmin,
                                                const float* __restrict__ thrv,
                                                unsigned* __restrict__ tcnt,
                                                int* __restrict__ tlist) {
  const int t = blockIdx.x >> 3;
  const int slice = blockIdx.x & 7;
  const int tid = threadIdx.x;
  const int m0 = slice * (kN / 8);
  const float* tm = tmin + (size_t)t * kN;

  unsigned okbits = 0;
#pragma unroll
  for (int it = 0; it < 16; ++it) {
    const int m = m0 + it * 256 + tid;
    if (tm[m] <= thrv[m]) okbits |= (1u << it);
  }
  const int cnt = __popc(okbits);

  __shared__ int itmp[256];
  __shared__ int sbase;
  itmp[tid] = cnt;
  __syncthreads();
  for (int off = 1; off < 256; off <<= 1) {
    const int add = (tid >= off) ? itmp[tid - off] : 0;
    __syncthreads();
    itmp[tid] += add;
    __syncthreads();
  }
  if (tid == 255) sbase = (int)atomicAdd(&tcnt[t], (unsigned)itmp[255]);
  __syncthreads();

  int pos = sbase + itmp[tid] - cnt;
  int* tl = tlist + (size_t)t * kN;
#pragma unroll
  for (int it = 0; it < 16; ++it)
    if ((okbits >> it) & 1u) tl[pos++] = m0 + it * 256 + tid;
}

// ---------------- gathered-row MFMA re-score over surviving pairs ----------
__global__ __launch_bounds__(256, 4) void score_gather(
    const _Float16* __restrict__ z16, const _Float16* __restrict__ w16,
    const float* __restrict__ cw, const float* __restrict__ thrv,
    const unsigned* __restrict__ tcnt, const int* __restrict__ tlist,
    unsigned* __restrict__ segcnt, int2* __restrict__ flat) {
  __shared__ _Float16 Asg[128 * 64];
  __shared__ _Float16 Bsg[128 * 64];
  __shared__ int itmp[256];
  __shared__ int sbase;

  const int tid = threadIdx.x;
  const int wid = tid >> 6;
  const int lane = tid & 63;
  const int l16 = lane & 15;
  const int quad = lane >> 4;
  const int t = blockIdx.x & (NTIL - 1);
  const int j0 = blockIdx.x >> 6;  // 0..JSLOT-1
  const int n0 = t * 128;
  const int rowbase = (wid >> 1) * 64;
  const int colbase = (wid & 1) * 64;
  const int ct = (int)tcnt[t];
  if (j0 * 128 >= ct) return;
  const int bucket = blockIdx.x & (NSEG - 1);  // spread skewed tiles
  const int* rlist = tlist + (size_t)t * kN;

  float cwv[4];
#pragma unroll
  for (int nt = 0; nt < 4; ++nt)
    cwv[nt] = cw[n0 + colbase + nt * 16 + l16];

  for (int chunk = j0; chunk * 128 < ct; chunk += JSLOT) {
    const int base = chunk * 128;
    floatx4 acc[4][4];
#pragma unroll
    for (int a = 0; a < 4; ++a)
#pragma unroll
      for (int b = 0; b < 4; ++b) acc[a][b] = (floatx4){0.f, 0.f, 0.f, 0.f};

    for (int kt = 0; kt < 4; ++kt) {
      const int d0 = kt * 64;
      __syncthreads();
#pragma unroll
      for (int p = 0; p < 4; ++p) {  // A: 128 gathered rows x 64 d
        const int q = p * 4 + wid;
        const int r = q * 8 + (lane >> 3);
        const int c = (lane & 7) ^ (r & 7);
        int gi = base + r;
        if (gi >= ct) gi = base;  // pad with dup of first row in chunk
        gload16(z16 + (size_t)rlist[gi] * kD + d0 + c * 8, &Asg[q * 512]);
      }
#pragma unroll
      for (int p = 0; p < 4; ++p) {  // B: 128 codes x 64 d
        const int q = p * 4 + wid;
        const int r = q * 8 + (lane >> 3);
        const int c = (lane & 7) ^ (r & 7);
        gload16(w16 + (size_t)(n0 + r) * kD + d0 + c * 8, &Bsg[q * 512]);
      }
      __syncthreads();
#pragma unroll
      for (int kc = 0; kc < 2; ++kc) {
        half8 af[4], bfr[4];
#pragma unroll
        for (int mt = 0; mt < 4; ++mt) {
          const int row = rowbase + mt * 16 + l16;
          const int j = (kc * 4 + quad) ^ (row & 7);
          af[mt] = *(const half8*)&Asg[row * 64 + j * 8];
        }
#pragma unroll
        for (int nt = 0; nt < 4; ++nt) {
          const int row = colbase + nt * 16 + l16;
          const int j = (kc * 4 + quad) ^ (row & 7);
          bfr[nt] = *(const half8*)&Bsg[row * 64 + j * 8];
        }
#pragma unroll
        for (int mt = 0; mt < 4; ++mt)
#pragma unroll
          for (int nt = 0; nt < 4; ++nt)
            acc[mt][nt] = __builtin_amdgcn_mfma_f32_16x16x32_f16(
                af[mt], bfr[nt], acc[mt][nt], 0, 0, 0);
      }
    }

    // ---- block-aggregated candidate insert ----
    unsigned long long cmask = 0ull;
    int ccnt = 0;
    int mrow[16];
#pragma unroll
    for (int mt = 0; mt < 4; ++mt) {
#pragma unroll
      for (int r = 0; r < 4; ++r) {
        int gi = base + rowbase + mt * 16 + quad * 4 + r;
        const bool vrow = (gi < ct);
        if (!vrow) gi = base;
        const int m = rlist[gi];
        mrow[mt * 4 + r] = m;
        const float th = thrv[m];
#pragma unroll
        for (int nt = 0; nt < 4; ++nt) {
          const float s = fmaf(acc[mt][nt][r], -1.220703125e-4f, cwv[nt]);
          if (vrow && s <= th) {
            cmask |= 1ull << (mt * 16 + r * 4 + nt);
            ++ccnt;
          }
        }
      }
    }
    __syncthreads();  // itmp reuse: prior-chunk reads complete
    itmp[tid] = ccnt;
    __syncthreads();
    for (int off = 1; off < 256; off <<= 1) {
      const int add = (tid >= off) ? itmp[tid - off] : 0;
      __syncthreads();
      itmp[tid] += add;
      __syncthreads();
    }
    if (tid == 255)
      sbase = itmp[255] ? (int)atomicAdd(&segcnt[bucket], (unsigned)itmp[255])
                        : 0;
    __syncthreads();
    if (cmask) {
      int pos = sbase + itmp[tid] - ccnt;
#pragma unroll
      for (int mt = 0; mt < 4; ++mt) {
#pragma unroll
        for (int r = 0; r < 4; ++r) {
          const int m = mrow[mt * 4 + r];
#pragma unroll
          for (int nt = 0; nt < 4; ++nt) {
            if ((cmask >> (mt * 16 + r * 4 + nt)) & 1ull) {
              if ((unsigned)pos < (unsigned)SEGCAP)
                flat[(size_t)bucket * SEGCAP + pos] =
                    make_int2(m, n0 + colbase + nt * 16 + l16);
              ++pos;
            }
          }
        }
      }
    }
  }
}

// ---------------- exact fp32-chain dist per candidate (segmented) ----------
__global__ __launch_bounds__(256) void exact_kernel(
    const float* __restrict__ z, const float* __restrict__ emb,
    const float* __restrict__ sz, const float* __restrict__ cw,
    const int2* __restrict__ flat, const unsigned* __restrict__ segcnt,
    unsigned long long* __restrict__ rkey) {
#pragma clang fp contract(off)
  const int i = blockIdx.x * 256 + threadIdx.x;
  const int seg = i >> 14;           // SEGCAP = 16384
  const int off = i & (SEGCAP - 1);
  unsigned cnt = segcnt[seg];
  if (cnt > (unsigned)SEGCAP) cnt = SEGCAP;
  if (off >= (int)cnt) return;
  const int2 c = flat[(size_t)seg * SEGCAP + off];
  const int m = c.x, n = c.y;
  const float* zrow = z + (size_t)m * kD;
  const float* wrow = emb + (size_t)n * kD;
  float a = 0.f;
  for (int d4 = 0; d4 < kD; d4 += 4) {
    const float4 zv = *(const float4*)&zrow[d4];
    const float4 wv = *(const float4*)&wrow[d4];
    a = __builtin_fmaf(zv.x, wv.x, a);
    a = __builtin_fmaf(zv.y, wv.y, a);
    a = __builtin_fmaf(zv.z, wv.z, a);
    a = __builtin_fmaf(zv.w, wv.w, a);
  }
  const float u = sz[m] - 2.0f * a;
  const float dist = u + cw[n];
  const unsigned long long key =
      ((unsigned long long)fmap(dist) << 32) | (unsigned)n;
  atomicMin(&rkey[m], key);  // equal dist -> lower n (numpy first-index)
}

// ---------------- finalize idx + hist + z_q_st + commit partials ----------
__global__ __launch_bounds__(256) void finalize_zq(
    const unsigned long long* __restrict__ rkey, const float* __restrict__ z,
    const float* __restrict__ emb, int* __restrict__ idxg,
    float* __restrict__ out_idx, int* __restrict__ hist,
    float* __restrict__ out_zq, double* __restrict__ part) {
#pragma clang fp contract(off)
  const int n = blockIdx.x;
  const int d = threadIdx.x;
  const int k = (int)(rkey[n] & 0xffffffffu);
  if (d == 0) {
    idxg[n] = k;
    out_idx[n] = (float)k;
    atomicAdd(&hist[k], 1);
  }
  const float zv = z[(size_t)n * kD + d];
  const float q = emb[(size_t)k * kD + d];
  out_zq[(size_t)n * kD + d] = zv + (q - zv);
  const float diff = zv - q;
  double v = (double)diff * (double)diff;
#pragma unroll
  for (int m = 32; m; m >>= 1) v += __shfl_xor(v, m);
  __shared__ double p4[4];
  if ((d & 63) == 0) p4[d >> 6] = v;
  __syncthreads();
  if (d == 0) part[n] = p4[0] + p4[1] + p4[2] + p4[3];
}

// ---------------- pre-reduce commit partials: 32768 -> 64 ------------------
__global__ __launch_bounds__(256) void reduce_part(
    const double* __restrict__ part, double* __restrict__ part2) {
#pragma clang fp contract(off)
  const int b = blockIdx.x;  // 64
  const int tid = threadIdx.x;
  double s = part[b * 512 + tid] + part[b * 512 + 256 + tid];
#pragma unroll
  for (int m = 32; m; m >>= 1) s += __shfl_xor(s, m);
  __shared__ double p4[4];
  if ((tid & 63) == 0) p4[tid >> 6] = s;
  __syncthreads();
  if (tid == 0) part2[b] = p4[0] + p4[1] + p4[2] + p4[3];
}

// ---------------- single-block: commit reduce + newcount + nsum + prefix ----
__global__ __launch_bounds__(256) void mid_k(
    const double* __restrict__ part2, float* __restrict__ out_com,
    const int* __restrict__ hist, const float* __restrict__ ec,
    float* __restrict__ out_cnt, double* __restrict__ nsum,
    int* __restrict__ offs, int* __restrict__ cursor) {
#pragma clang fp contract(off)
  const int t = threadIdx.x;
  __shared__ double dtmp[4];
  __shared__ int itmp[256];

  double s = (t < 64) ? part2[t] : 0.0;
#pragma unroll
  for (int m = 32; m; m >>= 1) s += __shfl_xor(s, m);
  if ((t & 63) == 0) dtmp[t >> 6] = s;
  __syncthreads();
  if (t == 0)
    out_com[0] = (float)(0.25 * (dtmp[0] + dtmp[1] + dtmp[2] + dtmp[3]) /
                         (double)((size_t)kN * kD));
  __syncthreads();

  const int base = t * 32;
  double ns = 0.0;
  int run = 0;
  for (int c = 0; c < 32; ++c) {
    const int k = base + c;
    const float nc = 0.99f * ec[k] + 0.01f * (float)hist[k];
    out_cnt[k] = nc;
    ns += (double)nc;
    run += hist[k];
  }
  itmp[t] = run;
  __syncthreads();
  for (int off = 1; off < 256; off <<= 1) {
    const int add = (t >= off) ? itmp[t - off] : 0;
    __syncthreads();
    itmp[t] += add;
    __syncthreads();
  }
  int run2 = itmp[t] - run;
  for (int c = 0; c < 32; ++c) {
    const int k = base + c;
    offs[k] = run2;
    cursor[k] = run2;
    run2 += hist[k];
  }
#pragma unroll
  for (int m = 32; m; m >>= 1) ns += __shfl_xor(ns, m);
  if ((t & 63) == 0) dtmp[t >> 6] = ns;
  __syncthreads();
  if (t == 0) *nsum = dtmp[0] + dtmp[1] + dtmp[2] + dtmp[3];
}

// ---------------- scatter rows into per-code lists ----------------
__global__ __launch_bounds__(256) void scatter_k(const int* __restrict__ idxg,
                                                 int* __restrict__ cursor,
                                                 int* __restrict__ rowlist) {
  const int r = blockIdx.x * 256 + threadIdx.x;
  const int k = idxg[r];
  const int pos = atomicAdd(&cursor[k], 1);
  rowlist[pos] = r;
}

// ---------------- new_avg + new_embed via gathered row sums ----------------
__global__ __launch_bounds__(256) void newavg_k(
    const float* __restrict__ z, const float* __restrict__ ea,
    const int* __restrict__ hist, const int* __restrict__ offs,
    const int* __restrict__ rowlist, const float* __restrict__ out_cnt,
    const double* __restrict__ nsum, float* __restrict__ out_emb,
    float* __restrict__ out_avg) {
#pragma clang fp contract(off)
  const int k = blockIdx.x;
  const int d = threadIdx.x;
  const int c = hist[k];
  const int off = offs[k];
  float s = 0.f;
  for (int j = 0; j < c; ++j)
    s += z[(size_t)rowlist[off + j] * kD + d];
  const size_t o = (size_t)k * kD + d;
  const float na = 0.99f * ea[o] + 0.01f * s;
  out_avg[o] = na;
  const float nf = (float)(*nsum);
  const float nc = out_cnt[k];
  const float keps = 0.08192f;  // fl(K * EPS)
  const float cs = (nc + 1e-5f) / (nf + keps) * nf;
  out_emb[o] = na / cs;
}

extern "C" void kernel_launch(void* const* d_in, const int* in_sizes, int n_in,
                              void* d_out, int out_size, void* d_ws, size_t ws_size,
                              hipStream_t stream) {
  const float* z_e       = (const float*)d_in[0];
  const float* embedding = (const float*)d_in[1];
  const float* ema_count = (const float*)d_in[2];
  const float* ema_avg   = (const float*)d_in[3];

  char* ws = (char*)d_ws;
  int*    hist   = (int*)(ws + OFF_HIST);
  double* nsum   = (double*)(ws + OFF_NS);
  unsigned* segcnt = (unsigned*)(ws + OFF_SEG);
  unsigned* tcnt = (unsigned*)(ws + OFF_TCNT);
  unsigned long long* rkey = (unsigned long long*)(ws + OFF_RKEY);
  float*  sz     = (float*)(ws + OFF_SZ);
  float*  cw     = (float*)(ws + OFF_CW);
  float*  thrv   = (float*)(ws + OFF_THR);
  _Float16* z16  = (_Float16*)(ws + OFF_Z16);
  _Float16* w16  = (_Float16*)(ws + OFF_W16);
  float*  tmin   = (float*)(ws + OFF_TMIN);
  int2*   flat   = (int2*)(ws + OFF_FLAT);
  int*    tlist  = (int*)(ws + OFF_TLIST);
  int*    idxg   = (int*)(ws + OFF_IDX);
  int*    offs   = (int*)(ws + OFF_OFFS);
  int*    cursor = (int*)(ws + OFF_CUR);
  int*    rowlist= (int*)(ws + OFF_ROWL);
  double* part   = (double*)(ws + OFF_PART);
  double* part2  = (double*)(ws + OFF_PART2);

  float* out_zq  = (float*)d_out;
  float* out_com = out_zq + (size_t)kN * kD;
  float* out_idx = out_com + 1;
  float* out_emb = out_idx + kN;
  float* out_cnt = out_emb + (size_t)kK * kD;
  float* out_avg = out_cnt + kK;

  hipMemsetAsync(ws, 0, ZERO_BYTES, stream);
  hipMemsetAsync(ws + OFF_RKEY, 0xFF, FF_BYTES, stream);

  prep2<<<1280, 256, 0, stream>>>(z_e, embedding, z16, w16, sz, cw);
  score_min<<<(kN / 128) * (kK / 128), 256, 0, stream>>>(z16, w16, cw, tmin);
  rowmin_k<<<kN / 64, 256, 0, stream>>>(tmin, thrv);
  append_k<<<NTIL * 8, 256, 0, stream>>>(tmin, thrv, tcnt, tlist);
  score_gather<<<NTIL * JSLOT, 256, 0, stream>>>(z16, w16, cw, thrv, tcnt,
                                                 tlist, segcnt, flat);
  exact_kernel<<<(NSEG * SEGCAP) / 256, 256, 0, stream>>>(
      z_e, embedding, sz, cw, flat, segcnt, rkey);
  finalize_zq<<<kN, 256, 0, stream>>>(rkey, z_e, embedding, idxg, out_idx,
                                      hist, out_zq, part);
  reduce_part<<<64, 256, 0, stream>>>(part, part2);
  mid_k<<<1, 256, 0, stream>>>(part2, out_com, hist, ema_count, out_cnt, nsum,
                               offs, cursor);
  scatter_k<<<kN / 256, 256, 0, stream>>>(idxg, cursor, rowlist);
  newavg_k<<<kK, 256, 0, stream>>>(z_e, ema_avg, hist, offs, rowlist, out_cnt,
                                   nsum, out_emb, out_avg);
}

// Round 8
// 581.783 us; speedup vs baseline: 1.1111x; 1.0173x over previous
//
#include <hip/hip_runtime.h>

// VectorQuantizerEMA  N=32768 K=8192 D=256  fp32
// Outputs: z_q_st[N*D], commitment[1], idx[N], new_embed[K*D], new_count[K], new_avg[K*D]
//
// Single full fp16 MFMA score GEMM (z16 * (w*2^14)16):
//   score_min: 128x128 tile, BK=64, 4 waves, 2-barrier K-loop. XCD-BANDED
//              block swizzle: xcd = blockIdx&7 owns m-tiles [32*xcd,32*xcd+32)
//              (2 MB of z16 -> fits 4 MB per-XCD L2) and sweeps all 64
//              n-tiles n-outer/m-inner. Staging traffic (2.1 GB/dispatch,
//              10.7 TB/s at 197us = LLC-BW-bound before) now served by
//              XCD-private L2. Pure index bijection - no numerical change.
//              Per-(row,128-code-tile) min -> tmin[ntile][row].
//   rowmin_k:  thr[m] = min over 64 tile-mins + WWIN.
//   append_k:  512 blocks: 16-bit survivor masks, block prefix-scan, ONE
//              global atomicAdd per block.
//   score_gather: gathered-row 128x128 MFMA re-score ONLY for surviving pairs
//              (same per-fragment K-chain -> bit-identical scores);
//              block-aggregated insert (one atomicAdd per block-chunk).
// Then: exact fp32-chain dist per candidate -> atomicMin (fmap(dist)<<32|n)
// = numpy first-index tie-break. EMA epilogue via inverted index.
//
// Candidate-set equivalence: s(m,n) <= thr(m) implies tilemin(m,tile(n)) <=
// s <= thr, so the tile survives and (m,n) is enumerated by score_gather with
// the bit-identical s -> identical candidate set. tlist/flat order is
// irrelevant: downstream is order-independent atomicMin resolution.
//
// History: r6 8-phase 256^2 port regressed (197->276us: 4 K-tiles can't fill
// the pipeline, 1 block/CU); r7 LDS-shrink to 32KB didn't raise occupancy
// (42% both) and score_min ran 208us with anomalous FETCH growth -> cache
// residency, not schedule/occupancy, is the binding constraint.

typedef _Float16 half8 __attribute__((ext_vector_type(8)));
typedef _Float16 half4 __attribute__((ext_vector_type(4)));
typedef __attribute__((ext_vector_type(4))) float floatx4;

namespace {
constexpr int kN = 32768;
constexpr int kK = 8192;
constexpr int kD = 256;
constexpr int NTIL = kK / 128;     // 64 code tiles
constexpr int JSLOT = 32;          // chunk-slots per tile in score_gather
constexpr int NSEG = 64;
constexpr int SEGCAP = 16384;      // int2 per segment; 64*16384 = 1M entries
constexpr float WWIN = 2.0e-4f;    // containment needs ~8.5e-5; 2.3x margin

// ---- workspace layout (bytes) ----
constexpr size_t OFF_HIST = 0;                                // int K
constexpr size_t OFF_NS   = OFF_HIST + (size_t)kK * 4;        // double
constexpr size_t OFF_SEG  = OFF_NS + 8;                       // uint NSEG
constexpr size_t OFF_TCNT = OFF_SEG + (size_t)NSEG * 4;       // uint NTIL
constexpr size_t ZERO_BYTES = OFF_TCNT + (size_t)NTIL * 4;
constexpr size_t OFF_RKEY = (ZERO_BYTES + 63) & ~(size_t)63;  // ull N, 0xFF
constexpr size_t FF_BYTES = (size_t)kN * 8;
constexpr size_t OFF_SZ   = OFF_RKEY + (size_t)kN * 8;        // float N
constexpr size_t OFF_CW   = OFF_SZ + (size_t)kN * 4;          // float K
constexpr size_t OFF_THR  = OFF_CW + (size_t)kK * 4;          // float N
constexpr size_t OFF_Z16  = OFF_THR + (size_t)kN * 4;         // f16 N*D
constexpr size_t OFF_W16  = OFF_Z16 + (size_t)kN * kD * 2;    // f16 K*D
// tmin (float NTIL*N = 8 MB) dead after append_k; flat (int2 NSEG*SEGCAP =
// 8 MB) live from score_gather on -> UNION the two regions.
constexpr size_t OFF_TMIN = OFF_W16 + (size_t)kK * kD * 2;
constexpr size_t OFF_FLAT = OFF_TMIN;
static_assert((size_t)NSEG * SEGCAP * 8 == (size_t)NTIL * kN * 4,
              "flat must fit exactly in tmin region");
constexpr size_t OFF_TLIST = OFF_TMIN + (size_t)NTIL * kN * 4; // int NTIL*N
constexpr size_t OFF_IDX  = OFF_TLIST + (size_t)NTIL * kN * 4; // int N
constexpr size_t OFF_OFFS = OFF_IDX + (size_t)kN * 4;         // int K
constexpr size_t OFF_CUR  = OFF_OFFS + (size_t)kK * 4;        // int K
constexpr size_t OFF_ROWL = OFF_CUR + (size_t)kK * 4;         // int N
constexpr size_t OFF_PART = OFF_ROWL + (size_t)kN * 4;        // double N
constexpr size_t OFF_PART2 = OFF_PART + (size_t)kN * 8;       // double 64
} // namespace

__device__ __forceinline__ unsigned fmap(float f) {
  unsigned u = __float_as_uint(f);
  return (u & 0x80000000u) ? ~u : (u | 0x80000000u);
}
__device__ __forceinline__ float funmap(unsigned m) {
  unsigned u = (m & 0x80000000u) ? (m & 0x7fffffffu) : ~m;
  return __uint_as_float(u);
}
__device__ __forceinline__ void gload16(const void* g, void* l) {
  __builtin_amdgcn_global_load_lds(
      (const __attribute__((address_space(1))) unsigned int*)g,
      (__attribute__((address_space(3))) unsigned int*)l, 16, 0, 0);
}

// ---------------- numpy AVX512 pairwise sum of squares ----------------
__device__ __forceinline__ float pw_block128_sq(const float* __restrict__ p) {
#pragma clang fp contract(off)
  float u[16];
#pragma unroll
  for (int l = 0; l < 16; ++l) {
    const float x0 = p[l] * p[l];
    const float x1 = p[16 + l] * p[16 + l];
    const float x2 = p[32 + l] * p[32 + l];
    const float x3 = p[48 + l] * p[48 + l];
    const float x4 = p[64 + l] * p[64 + l];
    const float x5 = p[80 + l] * p[80 + l];
    const float x6 = p[96 + l] * p[96 + l];
    const float x7 = p[112 + l] * p[112 + l];
    u[l] = ((x0 + x1) + (x2 + x3)) + ((x4 + x5) + (x6 + x7));
  }
  float t1[8], t2[4], t3[2];
#pragma unroll
  for (int l = 0; l < 8; ++l) t1[l] = u[l] + u[l + 8];
#pragma unroll
  for (int l = 0; l < 4; ++l) t2[l] = t1[l] + t1[l + 4];
#pragma unroll
  for (int l = 0; l < 2; ++l) t3[l] = t2[l] + t2[l + 2];
  return t3[0] + t3[1];
}

// ---------------- fused fp16 convert + numpy-order row sums (z and w) ------
__global__ __launch_bounds__(256) void prep2(const float* __restrict__ z,
                                             const float* __restrict__ w,
                                             _Float16* __restrict__ z16,
                                             _Float16* __restrict__ w16,
                                             float* __restrict__ sz,
                                             float* __restrict__ cw) {
  const bool isz = (blockIdx.x < 1024);
  const int b = isz ? blockIdx.x : blockIdx.x - 1024;
  const int nblocks = isz ? 1024 : 256;
  const int nrows = isz ? kN : kK;
  const float scale = isz ? 1.0f : 16384.0f;
  const float* x = isz ? z : w;
  _Float16* out16 = isz ? z16 : w16;
  float* sums = isz ? sz : cw;

  const int gid = b * 256 + threadIdx.x;
  const int gtot = nblocks * 256;
  const int nf4 = nrows * (kD / 4);
  for (int i = gid; i < nf4; i += gtot) {
    const float4 v = ((const float4*)x)[i];
    half4 h;
    h.x = (_Float16)(v.x * scale);
    h.y = (_Float16)(v.y * scale);
    h.z = (_Float16)(v.z * scale);
    h.w = (_Float16)(v.w * scale);
    ((half4*)out16)[i] = h;
  }
  for (int r = gid; r < nrows; r += gtot) {
    const float* p = x + (size_t)r * kD;
    sums[r] = pw_block128_sq(p) + pw_block128_sq(p + 128);
  }
}

// ---------------- MFMA score pass: 128x128 tile, BK=64, XCD-banded ---------
// grid 16384. xcd = blockIdx&7, slot = blockIdx>>3; m_tile = xcd*32+(slot&31)
// (per-XCD 2 MB A-band, L2-resident), n_tile = slot>>5 (B-tile L2-hot across
// its 32-slot run). Per-(row, ntile) block-min -> tmin[ntile*kN+row] (unique
// writer, coalesced, no atomics).
__global__ __launch_bounds__(256, 4) void score_min(
    const _Float16* __restrict__ z16, const _Float16* __restrict__ w16,
    const float* __restrict__ cw, float* __restrict__ tmin) {
  __shared__ _Float16 As[128 * 64];  // 16 KB, XOR-swizzled 16B chunks (8/row)
  __shared__ _Float16 Bs[128 * 64];  // 16 KB
  unsigned* pairmin = (unsigned*)As;  // 1 KB alias; As dead after K-loop

  const int tid = threadIdx.x;
  const int wid = tid >> 6;
  const int lane = tid & 63;
  const int l16 = lane & 15;
  const int quad = lane >> 4;
  const int xcd = blockIdx.x & 7;
  const int slot = blockIdx.x >> 3;
  const int m0 = (xcd * 32 + (slot & 31)) * 128;
  const int nt0 = slot >> 5;
  const int n0 = nt0 * 128;
  const int rowbase = (wid >> 1) * 64;
  const int colbase = (wid & 1) * 64;

  floatx4 acc[4][4];
#pragma unroll
  for (int a = 0; a < 4; ++a)
#pragma unroll
    for (int b = 0; b < 4; ++b) acc[a][b] = (floatx4){0.f, 0.f, 0.f, 0.f};

  for (int kt = 0; kt < 4; ++kt) {
    const int d0 = kt * 64;
    __syncthreads();  // prior-iter LDS reads complete before overwrite
#pragma unroll
    for (int p = 0; p < 4; ++p) {  // A: 128 rows x 64 d
      const int q = p * 4 + wid;
      const int r = q * 8 + (lane >> 3);
      const int c = (lane & 7) ^ (r & 7);
      gload16(z16 + (size_t)(m0 + r) * kD + d0 + c * 8, &As[q * 512]);
    }
#pragma unroll
    for (int p = 0; p < 4; ++p) {  // B: 128 codes x 64 d
      const int q = p * 4 + wid;
      const int r = q * 8 + (lane >> 3);
      const int c = (lane & 7) ^ (r & 7);
      gload16(w16 + (size_t)(n0 + r) * kD + d0 + c * 8, &Bs[q * 512]);
    }
    __syncthreads();  // drain staging
#pragma unroll
    for (int kc = 0; kc < 2; ++kc) {
      half8 af[4], bfr[4];
#pragma unroll
      for (int mt = 0; mt < 4; ++mt) {
        const int row = rowbase + mt * 16 + l16;
        const int j = (kc * 4 + quad) ^ (row & 7);
        af[mt] = *(const half8*)&As[row * 64 + j * 8];
      }
#pragma unroll
      for (int nt = 0; nt < 4; ++nt) {
        const int row = colbase + nt * 16 + l16;
        const int j = (kc * 4 + quad) ^ (row & 7);
        bfr[nt] = *(const half8*)&Bs[row * 64 + j * 8];
      }
#pragma unroll
      for (int mt = 0; mt < 4; ++mt)
#pragma unroll
        for (int nt = 0; nt < 4; ++nt)
          acc[mt][nt] = __builtin_amdgcn_mfma_f32_16x16x32_f16(
              af[mt], bfr[nt], acc[mt][nt], 0, 0, 0);
    }
  }
  __syncthreads();  // all waves done reading As before pairmin alias-write

  // ---- scores: w scaled by 2^14 -> -2*2^-14 = -2^-13 exactly ----
  float cwv[4];
#pragma unroll
  for (int nt = 0; nt < 4; ++nt)
    cwv[nt] = cw[n0 + colbase + nt * 16 + l16];

  // block row-min over this block's 128 codes -> tmin[nt0][row]
#pragma unroll
  for (int mt = 0; mt < 4; ++mt)
#pragma unroll
    for (int r = 0; r < 4; ++r) {
      float mn = 3.4e38f;
#pragma unroll
      for (int nt = 0; nt < 4; ++nt)
        mn = fminf(mn, fmaf(acc[mt][nt][r], -1.220703125e-4f, cwv[nt]));
#pragma unroll
      for (int off = 1; off < 16; off <<= 1)
        mn = fminf(mn, __shfl_xor(mn, off));
      if (l16 == 0) pairmin[wid * 64 + mt * 16 + quad * 4 + r] = fmap(mn);
    }
  __syncthreads();
  if ((wid & 1) == 0) {
    const unsigned v =
        min(pairmin[wid * 64 + lane], pairmin[(wid + 1) * 64 + lane]);
    tmin[(size_t)nt0 * kN + m0 + rowbase + lane] = funmap(v);
  }
}

// ---------------- row thresholds (no atomics) ------------------------------
__global__ __launch_bounds__(256) void rowmin_k(const float* __restrict__ tmin,
                                                float* __restrict__ thrv) {
  const int tid = threadIdx.x;
  const int w = tid >> 6;            // tile quarter 0..3
  const int lane = tid & 63;
  const int m = blockIdx.x * 64 + lane;

  float v[16];
#pragma unroll
  for (int i = 0; i < 16; ++i)
    v[i] = tmin[(size_t)(w * 16 + i) * kN + m];

  float mn = fminf(v[0], v[1]);
#pragma unroll
  for (int i = 2; i < 16; ++i) mn = fminf(mn, v[i]);

  __shared__ float red[4][64];
  red[w][lane] = mn;
  __syncthreads();
  if (w == 0)
    thrv[m] = fminf(fminf(red[0][lane], red[1][lane]),
                    fminf(red[2][lane], red[3][lane])) + WWIN;
}

// ---------------- survivor-list build (one atomic per block) ---------------
__global__ __launch_bounds__(256) void append_k(const float* __restrict__ tmin,
                                                const float* __restrict__ thrv,
                                                unsigned* __restrict__ tcnt,
                                                int* __restrict__ tlist) {
  const int t = blockIdx.x >> 3;
  const int slice = blockIdx.x & 7;
  const int tid = threadIdx.x;
  const int m0 = slice * (kN / 8);
  const float* tm = tmin + (size_t)t * kN;

  unsigned okbits = 0;
#pragma unroll
  for (int it = 0; it < 16; ++it) {
    const int m = m0 + it * 256 + tid;
    if (tm[m] <= thrv[m]) okbits |= (1u << it);
  }
  const int cnt = __popc(okbits);

  __shared__ int itmp[256];
  __shared__ int sbase;
  itmp[tid] = cnt;
  __syncthreads();
  for (int off = 1; off < 256; off <<= 1) {
    const int add = (tid >= off) ? itmp[tid - off] : 0;
    __syncthreads();
    itmp[tid] += add;
    __syncthreads();
  }
  if (tid == 255) sbase = (int)atomicAdd(&tcnt[t], (unsigned)itmp[255]);
  __syncthreads();

  int pos = sbase + itmp[tid] - cnt;
  int* tl = tlist + (size_t)t * kN;
#pragma unroll
  for (int it = 0; it < 16; ++it)
    if ((okbits >> it) & 1u) tl[pos++] = m0 + it * 256 + tid;
}

// ---------------- gathered-row MFMA re-score over surviving pairs ----------
__global__ __launch_bounds__(256, 4) void score_gather(
    const _Float16* __restrict__ z16, const _Float16* __restrict__ w16,
    const float* __restrict__ cw, const float* __restrict__ thrv,
    const unsigned* __restrict__ tcnt, const int* __restrict__ tlist,
    unsigned* __restrict__ segcnt, int2* __restrict__ flat) {
  __shared__ _Float16 Asg[128 * 64];
  __shared__ _Float16 Bsg[128 * 64];
  __shared__ int itmp[256];
  __shared__ int sbase;

  const int tid = threadIdx.x;
  const int wid = tid >> 6;
  const int lane = tid & 63;
  const int l16 = lane & 15;
  const int quad = lane >> 4;
  const int t = blockIdx.x & (NTIL - 1);
  const int j0 = blockIdx.x >> 6;  // 0..JSLOT-1
  const int n0 = t * 128;
  const int rowbase = (wid >> 1) * 64;
  const int colbase = (wid & 1) * 64;
  const int ct = (int)tcnt[t];
  if (j0 * 128 >= ct) return;
  const int bucket = blockIdx.x & (NSEG - 1);  // spread skewed tiles
  const int* rlist = tlist + (size_t)t * kN;

  float cwv[4];
#pragma unroll
  for (int nt = 0; nt < 4; ++nt)
    cwv[nt] = cw[n0 + colbase + nt * 16 + l16];

  for (int chunk = j0; chunk * 128 < ct; chunk += JSLOT) {
    const int base = chunk * 128;
    floatx4 acc[4][4];
#pragma unroll
    for (int a = 0; a < 4; ++a)
#pragma unroll
      for (int b = 0; b < 4; ++b) acc[a][b] = (floatx4){0.f, 0.f, 0.f, 0.f};

    for (int kt = 0; kt < 4; ++kt) {
      const int d0 = kt * 64;
      __syncthreads();
#pragma unroll
      for (int p = 0; p < 4; ++p) {  // A: 128 gathered rows x 64 d
        const int q = p * 4 + wid;
        const int r = q * 8 + (lane >> 3);
        const int c = (lane & 7) ^ (r & 7);
        int gi = base + r;
        if (gi >= ct) gi = base;  // pad with dup of first row in chunk
        gload16(z16 + (size_t)rlist[gi] * kD + d0 + c * 8, &Asg[q * 512]);
      }
#pragma unroll
      for (int p = 0; p < 4; ++p) {  // B: 128 codes x 64 d
        const int q = p * 4 + wid;
        const int r = q * 8 + (lane >> 3);
        const int c = (lane & 7) ^ (r & 7);
        gload16(w16 + (size_t)(n0 + r) * kD + d0 + c * 8, &Bsg[q * 512]);
      }
      __syncthreads();
#pragma unroll
      for (int kc = 0; kc < 2; ++kc) {
        half8 af[4], bfr[4];
#pragma unroll
        for (int mt = 0; mt < 4; ++mt) {
          const int row = rowbase + mt * 16 + l16;
          const int j = (kc * 4 + quad) ^ (row & 7);
          af[mt] = *(const half8*)&Asg[row * 64 + j * 8];
        }
#pragma unroll
        for (int nt = 0; nt < 4; ++nt) {
          const int row = colbase + nt * 16 + l16;
          const int j = (kc * 4 + quad) ^ (row & 7);
          bfr[nt] = *(const half8*)&Bsg[row * 64 + j * 8];
        }
#pragma unroll
        for (int mt = 0; mt < 4; ++mt)
#pragma unroll
          for (int nt = 0; nt < 4; ++nt)
            acc[mt][nt] = __builtin_amdgcn_mfma_f32_16x16x32_f16(
                af[mt], bfr[nt], acc[mt][nt], 0, 0, 0);
      }
    }

    // ---- block-aggregated candidate insert ----
    unsigned long long cmask = 0ull;
    int ccnt = 0;
    int mrow[16];
#pragma unroll
    for (int mt = 0; mt < 4; ++mt) {
#pragma unroll
      for (int r = 0; r < 4; ++r) {
        int gi = base + rowbase + mt * 16 + quad * 4 + r;
        const bool vrow = (gi < ct);
        if (!vrow) gi = base;
        const int m = rlist[gi];
        mrow[mt * 4 + r] = m;
        const float th = thrv[m];
#pragma unroll
        for (int nt = 0; nt < 4; ++nt) {
          const float s = fmaf(acc[mt][nt][r], -1.220703125e-4f, cwv[nt]);
          if (vrow && s <= th) {
            cmask |= 1ull << (mt * 16 + r * 4 + nt);
            ++ccnt;
          }
        }
      }
    }
    __syncthreads();  // itmp reuse: prior-chunk reads complete
    itmp[tid] = ccnt;
    __syncthreads();
    for (int off = 1; off < 256; off <<= 1) {
      const int add = (tid >= off) ? itmp[tid - off] : 0;
      __syncthreads();
      itmp[tid] += add;
      __syncthreads();
    }
    if (tid == 255)
      sbase = itmp[255] ? (int)atomicAdd(&segcnt[bucket], (unsigned)itmp[255])
                        : 0;
    __syncthreads();
    if (cmask) {
      int pos = sbase + itmp[tid] - ccnt;
#pragma unroll
      for (int mt = 0; mt < 4; ++mt) {
#pragma unroll
        for (int r = 0; r < 4; ++r) {
          const int m = mrow[mt * 4 + r];
#pragma unroll
          for (int nt = 0; nt < 4; ++nt) {
            if ((cmask >> (mt * 16 + r * 4 + nt)) & 1ull) {
              if ((unsigned)pos < (unsigned)SEGCAP)
                flat[(size_t)bucket * SEGCAP + pos] =
                    make_int2(m, n0 + colbase + nt * 16 + l16);
              ++pos;
            }
          }
        }
      }
    }
  }
}

// ---------------- exact fp32-chain dist per candidate (segmented) ----------
__global__ __launch_bounds__(256) void exact_kernel(
    const float* __restrict__ z, const float* __restrict__ emb,
    const float* __restrict__ sz, const float* __restrict__ cw,
    const int2* __restrict__ flat, const unsigned* __restrict__ segcnt,
    unsigned long long* __restrict__ rkey) {
#pragma clang fp contract(off)
  const int i = blockIdx.x * 256 + threadIdx.x;
  const int seg = i >> 14;           // SEGCAP = 16384
  const int off = i & (SEGCAP - 1);
  unsigned cnt = segcnt[seg];
  if (cnt > (unsigned)SEGCAP) cnt = SEGCAP;
  if (off >= (int)cnt) return;
  const int2 c = flat[(size_t)seg * SEGCAP + off];
  const int m = c.x, n = c.y;
  const float* zrow = z + (size_t)m * kD;
  const float* wrow = emb + (size_t)n * kD;
  float a = 0.f;
  for (int d4 = 0; d4 < kD; d4 += 4) {
    const float4 zv = *(const float4*)&zrow[d4];
    const float4 wv = *(const float4*)&wrow[d4];
    a = __builtin_fmaf(zv.x, wv.x, a);
    a = __builtin_fmaf(zv.y, wv.y, a);
    a = __builtin_fmaf(zv.z, wv.z, a);
    a = __builtin_fmaf(zv.w, wv.w, a);
  }
  const float u = sz[m] - 2.0f * a;
  const float dist = u + cw[n];
  const unsigned long long key =
      ((unsigned long long)fmap(dist) << 32) | (unsigned)n;
  atomicMin(&rkey[m], key);  // equal dist -> lower n (numpy first-index)
}

// ---------------- finalize idx + hist + z_q_st + commit partials ----------
__global__ __launch_bounds__(256) void finalize_zq(
    const unsigned long long* __restrict__ rkey, const float* __restrict__ z,
    const float* __restrict__ emb, int* __restrict__ idxg,
    float* __restrict__ out_idx, int* __restrict__ hist,
    float* __restrict__ out_zq, double* __restrict__ part) {
#pragma clang fp contract(off)
  const int n = blockIdx.x;
  const int d = threadIdx.x;
  const int k = (int)(rkey[n] & 0xffffffffu);
  if (d == 0) {
    idxg[n] = k;
    out_idx[n] = (float)k;
    atomicAdd(&hist[k], 1);
  }
  const float zv = z[(size_t)n * kD + d];
  const float q = emb[(size_t)k * kD + d];
  out_zq[(size_t)n * kD + d] = zv + (q - zv);
  const float diff = zv - q;
  double v = (double)diff * (double)diff;
#pragma unroll
  for (int m = 32; m; m >>= 1) v += __shfl_xor(v, m);
  __shared__ double p4[4];
  if ((d & 63) == 0) p4[d >> 6] = v;
  __syncthreads();
  if (d == 0) part[n] = p4[0] + p4[1] + p4[2] + p4[3];
}

// ---------------- pre-reduce commit partials: 32768 -> 64 ------------------
__global__ __launch_bounds__(256) void reduce_part(
    const double* __restrict__ part, double* __restrict__ part2) {
#pragma clang fp contract(off)
  const int b = blockIdx.x;  // 64
  const int tid = threadIdx.x;
  double s = part[b * 512 + tid] + part[b * 512 + 256 + tid];
#pragma unroll
  for (int m = 32; m; m >>= 1) s += __shfl_xor(s, m);
  __shared__ double p4[4];
  if ((tid & 63) == 0) p4[tid >> 6] = s;
  __syncthreads();
  if (tid == 0) part2[b] = p4[0] + p4[1] + p4[2] + p4[3];
}

// ---------------- single-block: commit reduce + newcount + nsum + prefix ----
__global__ __launch_bounds__(256) void mid_k(
    const double* __restrict__ part2, float* __restrict__ out_com,
    const int* __restrict__ hist, const float* __restrict__ ec,
    float* __restrict__ out_cnt, double* __restrict__ nsum,
    int* __restrict__ offs, int* __restrict__ cursor) {
#pragma clang fp contract(off)
  const int t = threadIdx.x;
  __shared__ double dtmp[4];
  __shared__ int itmp[256];

  double s = (t < 64) ? part2[t] : 0.0;
#pragma unroll
  for (int m = 32; m; m >>= 1) s += __shfl_xor(s, m);
  if ((t & 63) == 0) dtmp[t >> 6] = s;
  __syncthreads();
  if (t == 0)
    out_com[0] = (float)(0.25 * (dtmp[0] + dtmp[1] + dtmp[2] + dtmp[3]) /
                         (double)((size_t)kN * kD));
  __syncthreads();

  const int base = t * 32;
  double ns = 0.0;
  int run = 0;
  for (int c = 0; c < 32; ++c) {
    const int k = base + c;
    const float nc = 0.99f * ec[k] + 0.01f * (float)hist[k];
    out_cnt[k] = nc;
    ns += (double)nc;
    run += hist[k];
  }
  itmp[t] = run;
  __syncthreads();
  for (int off = 1; off < 256; off <<= 1) {
    const int add = (t >= off) ? itmp[t - off] : 0;
    __syncthreads();
    itmp[t] += add;
    __syncthreads();
  }
  int run2 = itmp[t] - run;
  for (int c = 0; c < 32; ++c) {
    const int k = base + c;
    offs[k] = run2;
    cursor[k] = run2;
    run2 += hist[k];
  }
#pragma unroll
  for (int m = 32; m; m >>= 1) ns += __shfl_xor(ns, m);
  if ((t & 63) == 0) dtmp[t >> 6] = ns;
  __syncthreads();
  if (t == 0) *nsum = dtmp[0] + dtmp[1] + dtmp[2] + dtmp[3];
}

// ---------------- scatter rows into per-code lists ----------------
__global__ __launch_bounds__(256) void scatter_k(const int* __restrict__ idxg,
                                                 int* __restrict__ cursor,
                                                 int* __restrict__ rowlist) {
  const int r = blockIdx.x * 256 + threadIdx.x;
  const int k = idxg[r];
  const int pos = atomicAdd(&cursor[k], 1);
  rowlist[pos] = r;
}

// ---------------- new_avg + new_embed via gathered row sums ----------------
__global__ __launch_bounds__(256) void newavg_k(
    const float* __restrict__ z, const float* __restrict__ ea,
    const int* __restrict__ hist, const int* __restrict__ offs,
    const int* __restrict__ rowlist, const float* __restrict__ out_cnt,
    const double* __restrict__ nsum, float* __restrict__ out_emb,
    float* __restrict__ out_avg) {
#pragma clang fp contract(off)
  const int k = blockIdx.x;
  const int d = threadIdx.x;
  const int c = hist[k];
  const int off = offs[k];
  float s = 0.f;
  for (int j = 0; j < c; ++j)
    s += z[(size_t)rowlist[off + j] * kD + d];
  const size_t o = (size_t)k * kD + d;
  const float na = 0.99f * ea[o] + 0.01f * s;
  out_avg[o] = na;
  const float nf = (float)(*nsum);
  const float nc = out_cnt[k];
  const float keps = 0.08192f;  // fl(K * EPS)
  const float cs = (nc + 1e-5f) / (nf + keps) * nf;
  out_emb[o] = na / cs;
}

extern "C" void kernel_launch(void* const* d_in, const int* in_sizes, int n_in,
                              void* d_out, int out_size, void* d_ws, size_t ws_size,
                              hipStream_t stream) {
  const float* z_e       = (const float*)d_in[0];
  const float* embedding = (const float*)d_in[1];
  const float* ema_count = (const float*)d_in[2];
  const float* ema_avg   = (const float*)d_in[3];

  char* ws = (char*)d_ws;
  int*    hist   = (int*)(ws + OFF_HIST);
  double* nsum   = (double*)(ws + OFF_NS);
  unsigned* segcnt = (unsigned*)(ws + OFF_SEG);
  unsigned* tcnt = (unsigned*)(ws + OFF_TCNT);
  unsigned long long* rkey = (unsigned long long*)(ws + OFF_RKEY);
  float*  sz     = (float*)(ws + OFF_SZ);
  float*  cw     = (float*)(ws + OFF_CW);
  float*  thrv   = (float*)(ws + OFF_THR);
  _Float16* z16  = (_Float16*)(ws + OFF_Z16);
  _Float16* w16  = (_Float16*)(ws + OFF_W16);
  float*  tmin   = (float*)(ws + OFF_TMIN);
  int2*   flat   = (int2*)(ws + OFF_FLAT);
  int*    tlist  = (int*)(ws + OFF_TLIST);
  int*    idxg   = (int*)(ws + OFF_IDX);
  int*    offs   = (int*)(ws + OFF_OFFS);
  int*    cursor = (int*)(ws + OFF_CUR);
  int*    rowlist= (int*)(ws + OFF_ROWL);
  double* part   = (double*)(ws + OFF_PART);
  double* part2  = (double*)(ws + OFF_PART2);

  float* out_zq  = (float*)d_out;
  float* out_com = out_zq + (size_t)kN * kD;
  float* out_idx = out_com + 1;
  float* out_emb = out_idx + kN;
  float* out_cnt = out_emb + (size_t)kK * kD;
  float* out_avg = out_cnt + kK;

  hipMemsetAsync(ws, 0, ZERO_BYTES, stream);
  hipMemsetAsync(ws + OFF_RKEY, 0xFF, FF_BYTES, stream);

  prep2<<<1280, 256, 0, stream>>>(z_e, embedding, z16, w16, sz, cw);
  score_min<<<(kN / 128) * (kK / 128), 256, 0, stream>>>(z16, w16, cw, tmin);
  rowmin_k<<<kN / 64, 256, 0, stream>>>(tmin, thrv);
  append_k<<<NTIL * 8, 256, 0, stream>>>(tmin, thrv, tcnt, tlist);
  score_gather<<<NTIL * JSLOT, 256, 0, stream>>>(z16, w16, cw, thrv, tcnt,
                                                 tlist, segcnt, flat);
  exact_kernel<<<(NSEG * SEGCAP) / 256, 256, 0, stream>>>(
      z_e, embedding, sz, cw, flat, segcnt, rkey);
  finalize_zq<<<kN, 256, 0, stream>>>(rkey, z_e, embedding, idxg, out_idx,
                                      hist, out_zq, part);
  reduce_part<<<64, 256, 0, stream>>>(part, part2);
  mid_k<<<1, 256, 0, stream>>>(part2, out_com, hist, ema_count, out_cnt, nsum,
                               offs, cursor);
  scatter_k<<<kN / 256, 256, 0, stream>>>(idxg, cursor, rowlist);
  newavg_k<<<kK, 256, 0, stream>>>(z_e, ema_avg, hist, offs, rowlist, out_cnt,
                                   nsum, out_emb, out_avg);
}

// Round 9
// 566.820 us; speedup vs baseline: 1.1404x; 1.0264x over previous
//
#include <hip/hip_runtime.h>

// VectorQuantizerEMA  N=32768 K=8192 D=256  fp32
// Outputs: z_q_st[N*D], commitment[1], idx[N], new_embed[K*D], new_count[K], new_avg[K*D]
//
// Single full fp16 MFMA score GEMM (z16 * (w*2^14)16):
//   prep2:     fp16 convert + numpy-order row sums + ALL workspace init
//              (hist/segcnt/tcnt zero, rkey 0xFF) - replaces 2 memsets.
//   score_min: 128x128 tile, BK=64, 4 waves, 2-barrier K-loop (r5-best:
//              196.9us). STRUCTURE-BOUND at ~197us: r6 8-phase port (276us,
//              4 K-tiles can't fill pipeline), r7 LDS-shrink (208us, no occ
//              gain), r8 XCD-banding (201us, FETCH 160->27MB but time flat)
//              all failed to beat it; traffic/occupancy are not the limit.
//              Per-(row,128-code-tile) min -> tmin[ntile][row].
//   rowmin_k:  thr[m] = min over 64 tile-mins + WWIN.
//   append_k:  512 blocks: 16-bit survivor masks, block prefix-scan, ONE
//              global atomicAdd per block.
//   score_gather: gathered-row 128x128 MFMA re-score ONLY for surviving pairs
//              (same per-fragment K-chain -> bit-identical scores);
//              block-aggregated insert (one atomicAdd per block-chunk).
// Then: exact fp32-chain dist per candidate -> atomicMin (fmap(dist)<<32|n)
// = numpy first-index tie-break. EMA epilogue via inverted index.
//
// Candidate-set equivalence: s(m,n) <= thr(m) implies tilemin(m,tile(n)) <=
// s <= thr, so the tile survives and (m,n) is enumerated by score_gather with
// the bit-identical s -> identical candidate set. tlist/flat order is
// irrelevant: downstream is order-independent atomicMin resolution.

typedef _Float16 half8 __attribute__((ext_vector_type(8)));
typedef _Float16 half4 __attribute__((ext_vector_type(4)));
typedef __attribute__((ext_vector_type(4))) float floatx4;

namespace {
constexpr int kN = 32768;
constexpr int kK = 8192;
constexpr int kD = 256;
constexpr int NTIL = kK / 128;     // 64 code tiles
constexpr int JSLOT = 32;          // chunk-slots per tile in score_gather
constexpr int NSEG = 64;
constexpr int SEGCAP = 16384;      // int2 per segment; 64*16384 = 1M entries
constexpr float WWIN = 2.0e-4f;    // containment needs ~8.5e-5; 2.3x margin

// ---- workspace layout (bytes) ----
constexpr size_t OFF_HIST = 0;                                // int K
constexpr size_t OFF_NS   = OFF_HIST + (size_t)kK * 4;        // double
constexpr size_t OFF_SEG  = OFF_NS + 8;                       // uint NSEG
constexpr size_t OFF_TCNT = OFF_SEG + (size_t)NSEG * 4;       // uint NTIL
constexpr size_t ZERO_BYTES = OFF_TCNT + (size_t)NTIL * 4;
constexpr size_t OFF_RKEY = (ZERO_BYTES + 63) & ~(size_t)63;  // ull N
constexpr size_t OFF_SZ   = OFF_RKEY + (size_t)kN * 8;        // float N
constexpr size_t OFF_CW   = OFF_SZ + (size_t)kN * 4;          // float K
constexpr size_t OFF_THR  = OFF_CW + (size_t)kK * 4;          // float N
constexpr size_t OFF_Z16  = OFF_THR + (size_t)kN * 4;         // f16 N*D
constexpr size_t OFF_W16  = OFF_Z16 + (size_t)kN * kD * 2;    // f16 K*D
// tmin (float NTIL*N = 8 MB) dead after append_k; flat (int2 NSEG*SEGCAP =
// 8 MB) live from score_gather on -> UNION the two regions.
constexpr size_t OFF_TMIN = OFF_W16 + (size_t)kK * kD * 2;
constexpr size_t OFF_FLAT = OFF_TMIN;
static_assert((size_t)NSEG * SEGCAP * 8 == (size_t)NTIL * kN * 4,
              "flat must fit exactly in tmin region");
constexpr size_t OFF_TLIST = OFF_TMIN + (size_t)NTIL * kN * 4; // int NTIL*N
constexpr size_t OFF_IDX  = OFF_TLIST + (size_t)NTIL * kN * 4; // int N
constexpr size_t OFF_OFFS = OFF_IDX + (size_t)kN * 4;         // int K
constexpr size_t OFF_CUR  = OFF_OFFS + (size_t)kK * 4;        // int K
constexpr size_t OFF_ROWL = OFF_CUR + (size_t)kK * 4;         // int N
constexpr size_t OFF_PART = OFF_ROWL + (size_t)kN * 4;        // double N
constexpr size_t OFF_PART2 = OFF_PART + (size_t)kN * 8;       // double 64
} // namespace

__device__ __forceinline__ unsigned fmap(float f) {
  unsigned u = __float_as_uint(f);
  return (u & 0x80000000u) ? ~u : (u | 0x80000000u);
}
__device__ __forceinline__ float funmap(unsigned m) {
  unsigned u = (m & 0x80000000u) ? (m & 0x7fffffffu) : ~m;
  return __uint_as_float(u);
}
__device__ __forceinline__ void gload16(const void* g, void* l) {
  __builtin_amdgcn_global_load_lds(
      (const __attribute__((address_space(1))) unsigned int*)g,
      (__attribute__((address_space(3))) unsigned int*)l, 16, 0, 0);
}

// ---------------- numpy AVX512 pairwise sum of squares ----------------
__device__ __forceinline__ float pw_block128_sq(const float* __restrict__ p) {
#pragma clang fp contract(off)
  float u[16];
#pragma unroll
  for (int l = 0; l < 16; ++l) {
    const float x0 = p[l] * p[l];
    const float x1 = p[16 + l] * p[16 + l];
    const float x2 = p[32 + l] * p[32 + l];
    const float x3 = p[48 + l] * p[48 + l];
    const float x4 = p[64 + l] * p[64 + l];
    const float x5 = p[80 + l] * p[80 + l];
    const float x6 = p[96 + l] * p[96 + l];
    const float x7 = p[112 + l] * p[112 + l];
    u[l] = ((x0 + x1) + (x2 + x3)) + ((x4 + x5) + (x6 + x7));
  }
  float t1[8], t2[4], t3[2];
#pragma unroll
  for (int l = 0; l < 8; ++l) t1[l] = u[l] + u[l + 8];
#pragma unroll
  for (int l = 0; l < 4; ++l) t2[l] = t1[l] + t1[l + 4];
#pragma unroll
  for (int l = 0; l < 2; ++l) t3[l] = t2[l] + t2[l + 2];
  return t3[0] + t3[1];
}

// ------- fused fp16 convert + numpy-order row sums + workspace init -------
// grid 1280 (1024 z + 256 w). Init section replaces the two memsets (all
// consumers are later, stream-ordered).
__global__ __launch_bounds__(256) void prep2(
    const float* __restrict__ z, const float* __restrict__ w,
    _Float16* __restrict__ z16, _Float16* __restrict__ w16,
    float* __restrict__ sz, float* __restrict__ cw,
    int* __restrict__ hist, unsigned* __restrict__ segcnt,
    unsigned* __restrict__ tcnt, unsigned long long* __restrict__ rkey) {
  const int g = blockIdx.x * 256 + threadIdx.x;  // 0..327679
  if (g < kN) rkey[g] = ~0ull;
  if (g < kK) hist[g] = 0;
  if (g < NSEG) segcnt[g] = 0;
  if (g < NTIL) tcnt[g] = 0;

  const bool isz = (blockIdx.x < 1024);
  const int b = isz ? blockIdx.x : blockIdx.x - 1024;
  const int nblocks = isz ? 1024 : 256;
  const int nrows = isz ? kN : kK;
  const float scale = isz ? 1.0f : 16384.0f;
  const float* x = isz ? z : w;
  _Float16* out16 = isz ? z16 : w16;
  float* sums = isz ? sz : cw;

  const int gid = b * 256 + threadIdx.x;
  const int gtot = nblocks * 256;
  const int nf4 = nrows * (kD / 4);
  for (int i = gid; i < nf4; i += gtot) {
    const float4 v = ((const float4*)x)[i];
    half4 h;
    h.x = (_Float16)(v.x * scale);
    h.y = (_Float16)(v.y * scale);
    h.z = (_Float16)(v.z * scale);
    h.w = (_Float16)(v.w * scale);
    ((half4*)out16)[i] = h;
  }
  for (int r = gid; r < nrows; r += gtot) {
    const float* p = x + (size_t)r * kD;
    sums[r] = pw_block128_sq(p) + pw_block128_sq(p + 128);
  }
}

// ---------------- MFMA score pass: 128x128 tile, BK=64 ---------------------
// grid 16384, mtile INNER (blockIdx&255); per-(row, ntile) block-min written
// to tmin[ntile * kN + row] (unique writer, coalesced, no atomics).
__global__ __launch_bounds__(256, 4) void score_min(
    const _Float16* __restrict__ z16, const _Float16* __restrict__ w16,
    const float* __restrict__ cw, float* __restrict__ tmin) {
  __shared__ _Float16 As[128 * 64];  // 16 KB, XOR-swizzled 16B chunks (8/row)
  __shared__ _Float16 Bs[128 * 64];  // 16 KB
  __shared__ unsigned pairmin[4][64];

  const int tid = threadIdx.x;
  const int wid = tid >> 6;
  const int lane = tid & 63;
  const int l16 = lane & 15;
  const int quad = lane >> 4;
  const int m0 = (blockIdx.x & 255) * 128;
  const int nt0 = blockIdx.x >> 8;
  const int n0 = nt0 * 128;
  const int rowbase = (wid >> 1) * 64;
  const int colbase = (wid & 1) * 64;

  floatx4 acc[4][4];
#pragma unroll
  for (int a = 0; a < 4; ++a)
#pragma unroll
    for (int b = 0; b < 4; ++b) acc[a][b] = (floatx4){0.f, 0.f, 0.f, 0.f};

  for (int kt = 0; kt < 4; ++kt) {
    const int d0 = kt * 64;
    __syncthreads();  // prior-iter LDS reads complete before overwrite
#pragma unroll
    for (int p = 0; p < 4; ++p) {  // A: 128 rows x 64 d
      const int q = p * 4 + wid;
      const int r = q * 8 + (lane >> 3);
      const int c = (lane & 7) ^ (r & 7);
      gload16(z16 + (size_t)(m0 + r) * kD + d0 + c * 8, &As[q * 512]);
    }
#pragma unroll
    for (int p = 0; p < 4; ++p) {  // B: 128 codes x 64 d
      const int q = p * 4 + wid;
      const int r = q * 8 + (lane >> 3);
      const int c = (lane & 7) ^ (r & 7);
      gload16(w16 + (size_t)(n0 + r) * kD + d0 + c * 8, &Bs[q * 512]);
    }
    __syncthreads();  // drain staging
#pragma unroll
    for (int kc = 0; kc < 2; ++kc) {
      half8 af[4], bfr[4];
#pragma unroll
      for (int mt = 0; mt < 4; ++mt) {
        const int row = rowbase + mt * 16 + l16;
        const int j = (kc * 4 + quad) ^ (row & 7);
        af[mt] = *(const half8*)&As[row * 64 + j * 8];
      }
#pragma unroll
      for (int nt = 0; nt < 4; ++nt) {
        const int row = colbase + nt * 16 + l16;
        const int j = (kc * 4 + quad) ^ (row & 7);
        bfr[nt] = *(const half8*)&Bs[row * 64 + j * 8];
      }
#pragma unroll
      for (int mt = 0; mt < 4; ++mt)
#pragma unroll
        for (int nt = 0; nt < 4; ++nt)
          acc[mt][nt] = __builtin_amdgcn_mfma_f32_16x16x32_f16(
              af[mt], bfr[nt], acc[mt][nt], 0, 0, 0);
    }
  }

  // ---- scores: w scaled by 2^14 -> -2*2^-14 = -2^-13 exactly ----
  float cwv[4];
#pragma unroll
  for (int nt = 0; nt < 4; ++nt)
    cwv[nt] = cw[n0 + colbase + nt * 16 + l16];

  // block row-min over this block's 128 codes -> tmin[nt0][row]
#pragma unroll
  for (int mt = 0; mt < 4; ++mt)
#pragma unroll
    for (int r = 0; r < 4; ++r) {
      float mn = 3.4e38f;
#pragma unroll
      for (int nt = 0; nt < 4; ++nt)
        mn = fminf(mn, fmaf(acc[mt][nt][r], -1.220703125e-4f, cwv[nt]));
#pragma unroll
      for (int off = 1; off < 16; off <<= 1)
        mn = fminf(mn, __shfl_xor(mn, off));
      if (l16 == 0) pairmin[wid][mt * 16 + quad * 4 + r] = fmap(mn);
    }
  __syncthreads();
  if ((wid & 1) == 0) {
    const unsigned v = min(pairmin[wid][lane], pairmin[wid + 1][lane]);
    tmin[(size_t)nt0 * kN + m0 + rowbase + lane] = funmap(v);
  }
}

// ---------------- row thresholds (no atomics) ------------------------------
__global__ __launch_bounds__(256) void rowmin_k(const float* __restrict__ tmin,
                                                float* __restrict__ thrv) {
  const int tid = threadIdx.x;
  const int w = tid >> 6;            // tile quarter 0..3
  const int lane = tid & 63;
  const int m = blockIdx.x * 64 + lane;

  float v[16];
#pragma unroll
  for (int i = 0; i < 16; ++i)
    v[i] = tmin[(size_t)(w * 16 + i) * kN + m];

  float mn = fminf(v[0], v[1]);
#pragma unroll
  for (int i = 2; i < 16; ++i) mn = fminf(mn, v[i]);

  __shared__ float red[4][64];
  red[w][lane] = mn;
  __syncthreads();
  if (w == 0)
    thrv[m] = fminf(fminf(red[0][lane], red[1][lane]),
                    fminf(red[2][lane], red[3][lane])) + WWIN;
}

// ---------------- survivor-list build (one atomic per block) ---------------
__global__ __launch_bounds__(256) void append_k(const float* __restrict__ tmin,
                                                const float* __restrict__ thrv,
                                                unsigned* __restrict__ tcnt,
                                                int* __restrict__ tlist) {
  const int t = blockIdx.x >> 3;
  const int slice = blockIdx.x & 7;
  const int tid = threadIdx.x;
  const int m0 = slice * (kN / 8);
  const float* tm = tmin + (size_t)t * kN;

  unsigned okbits = 0;
#pragma unroll
  for (int it = 0; it < 16; ++it) {
    const int m = m0 + it * 256 + tid;
    if (tm[m] <= thrv[m]) okbits |= (1u << it);
  }
  const int cnt = __popc(okbits);

  __shared__ int itmp[256];
  __shared__ int sbase;
  itmp[tid] = cnt;
  __syncthreads();
  for (int off = 1; off < 256; off <<= 1) {
    const int add = (tid >= off) ? itmp[tid - off] : 0;
    __syncthreads();
    itmp[tid] += add;
    __syncthreads();
  }
  if (tid == 255) sbase = (int)atomicAdd(&tcnt[t], (unsigned)itmp[255]);
  __syncthreads();

  int pos = sbase + itmp[tid] - cnt;
  int* tl = tlist + (size_t)t * kN;
#pragma unroll
  for (int it = 0; it < 16; ++it)
    if ((okbits >> it) & 1u) tl[pos++] = m0 + it * 256 + tid;
}

// ---------------- gathered-row MFMA re-score over surviving pairs ----------
__global__ __launch_bounds__(256, 4) void score_gather(
    const _Float16* __restrict__ z16, const _Float16* __restrict__ w16,
    const float* __restrict__ cw, const float* __restrict__ thrv,
    const unsigned* __restrict__ tcnt, const int* __restrict__ tlist,
    unsigned* __restrict__ segcnt, int2* __restrict__ flat) {
  __shared__ _Float16 Asg[128 * 64];
  __shared__ _Float16 Bsg[128 * 64];
  __shared__ int itmp[256];
  __shared__ int sbase;

  const int tid = threadIdx.x;
  const int wid = tid >> 6;
  const int lane = tid & 63;
  const int l16 = lane & 15;
  const int quad = lane >> 4;
  const int t = blockIdx.x & (NTIL - 1);
  const int j0 = blockIdx.x >> 6;  // 0..JSLOT-1
  const int n0 = t * 128;
  const int rowbase = (wid >> 1) * 64;
  const int colbase = (wid & 1) * 64;
  const int ct = (int)tcnt[t];
  if (j0 * 128 >= ct) return;
  const int bucket = blockIdx.x & (NSEG - 1);  // spread skewed tiles
  const int* rlist = tlist + (size_t)t * kN;

  float cwv[4];
#pragma unroll
  for (int nt = 0; nt < 4; ++nt)
    cwv[nt] = cw[n0 + colbase + nt * 16 + l16];

  for (int chunk = j0; chunk * 128 < ct; chunk += JSLOT) {
    const int base = chunk * 128;
    floatx4 acc[4][4];
#pragma unroll
    for (int a = 0; a < 4; ++a)
#pragma unroll
      for (int b = 0; b < 4; ++b) acc[a][b] = (floatx4){0.f, 0.f, 0.f, 0.f};

    for (int kt = 0; kt < 4; ++kt) {
      const int d0 = kt * 64;
      __syncthreads();
#pragma unroll
      for (int p = 0; p < 4; ++p) {  // A: 128 gathered rows x 64 d
        const int q = p * 4 + wid;
        const int r = q * 8 + (lane >> 3);
        const int c = (lane & 7) ^ (r & 7);
        int gi = base + r;
        if (gi >= ct) gi = base;  // pad with dup of first row in chunk
        gload16(z16 + (size_t)rlist[gi] * kD + d0 + c * 8, &Asg[q * 512]);
      }
#pragma unroll
      for (int p = 0; p < 4; ++p) {  // B: 128 codes x 64 d
        const int q = p * 4 + wid;
        const int r = q * 8 + (lane >> 3);
        const int c = (lane & 7) ^ (r & 7);
        gload16(w16 + (size_t)(n0 + r) * kD + d0 + c * 8, &Bsg[q * 512]);
      }
      __syncthreads();
#pragma unroll
      for (int kc = 0; kc < 2; ++kc) {
        half8 af[4], bfr[4];
#pragma unroll
        for (int mt = 0; mt < 4; ++mt) {
          const int row = rowbase + mt * 16 + l16;
          const int j = (kc * 4 + quad) ^ (row & 7);
          af[mt] = *(const half8*)&Asg[row * 64 + j * 8];
        }
#pragma unroll
        for (int nt = 0; nt < 4; ++nt) {
          const int row = colbase + nt * 16 + l16;
          const int j = (kc * 4 + quad) ^ (row & 7);
          bfr[nt] = *(const half8*)&Bsg[row * 64 + j * 8];
        }
#pragma unroll
        for (int mt = 0; mt < 4; ++mt)
#pragma unroll
          for (int nt = 0; nt < 4; ++nt)
            acc[mt][nt] = __builtin_amdgcn_mfma_f32_16x16x32_f16(
                af[mt], bfr[nt], acc[mt][nt], 0, 0, 0);
      }
    }

    // ---- block-aggregated candidate insert ----
    unsigned long long cmask = 0ull;
    int ccnt = 0;
    int mrow[16];
#pragma unroll
    for (int mt = 0; mt < 4; ++mt) {
#pragma unroll
      for (int r = 0; r < 4; ++r) {
        int gi = base + rowbase + mt * 16 + quad * 4 + r;
        const bool vrow = (gi < ct);
        if (!vrow) gi = base;
        const int m = rlist[gi];
        mrow[mt * 4 + r] = m;
        const float th = thrv[m];
#pragma unroll
        for (int nt = 0; nt < 4; ++nt) {
          const float s = fmaf(acc[mt][nt][r], -1.220703125e-4f, cwv[nt]);
          if (vrow && s <= th) {
            cmask |= 1ull << (mt * 16 + r * 4 + nt);
            ++ccnt;
          }
        }
      }
    }
    __syncthreads();  // itmp reuse: prior-chunk reads complete
    itmp[tid] = ccnt;
    __syncthreads();
    for (int off = 1; off < 256; off <<= 1) {
      const int add = (tid >= off) ? itmp[tid - off] : 0;
      __syncthreads();
      itmp[tid] += add;
      __syncthreads();
    }
    if (tid == 255)
      sbase = itmp[255] ? (int)atomicAdd(&segcnt[bucket], (unsigned)itmp[255])
                        : 0;
    __syncthreads();
    if (cmask) {
      int pos = sbase + itmp[tid] - ccnt;
#pragma unroll
      for (int mt = 0; mt < 4; ++mt) {
#pragma unroll
        for (int r = 0; r < 4; ++r) {
          const int m = mrow[mt * 4 + r];
#pragma unroll
          for (int nt = 0; nt < 4; ++nt) {
            if ((cmask >> (mt * 16 + r * 4 + nt)) & 1ull) {
              if ((unsigned)pos < (unsigned)SEGCAP)
                flat[(size_t)bucket * SEGCAP + pos] =
                    make_int2(m, n0 + colbase + nt * 16 + l16);
              ++pos;
            }
          }
        }
      }
    }
  }
}

// ---------------- exact fp32-chain dist per candidate (segmented) ----------
__global__ __launch_bounds__(256) void exact_kernel(
    const float* __restrict__ z, const float* __restrict__ emb,
    const float* __restrict__ sz, const float* __restrict__ cw,
    const int2* __restrict__ flat, const unsigned* __restrict__ segcnt,
    unsigned long long* __restrict__ rkey) {
#pragma clang fp contract(off)
  const int i = blockIdx.x * 256 + threadIdx.x;
  const int seg = i >> 14;           // SEGCAP = 16384
  const int off = i & (SEGCAP - 1);
  unsigned cnt = segcnt[seg];
  if (cnt > (unsigned)SEGCAP) cnt = SEGCAP;
  if (off >= (int)cnt) return;
  const int2 c = flat[(size_t)seg * SEGCAP + off];
  const int m = c.x, n = c.y;
  const float* zrow = z + (size_t)m * kD;
  const float* wrow = emb + (size_t)n * kD;
  float a = 0.f;
  for (int d4 = 0; d4 < kD; d4 += 4) {
    const float4 zv = *(const float4*)&zrow[d4];
    const float4 wv = *(const float4*)&wrow[d4];
    a = __builtin_fmaf(zv.x, wv.x, a);
    a = __builtin_fmaf(zv.y, wv.y, a);
    a = __builtin_fmaf(zv.z, wv.z, a);
    a = __builtin_fmaf(zv.w, wv.w, a);
  }
  const float u = sz[m] - 2.0f * a;
  const float dist = u + cw[n];
  const unsigned long long key =
      ((unsigned long long)fmap(dist) << 32) | (unsigned)n;
  atomicMin(&rkey[m], key);  // equal dist -> lower n (numpy first-index)
}

// ---------------- finalize idx + hist + z_q_st + commit partials ----------
__global__ __launch_bounds__(256) void finalize_zq(
    const unsigned long long* __restrict__ rkey, const float* __restrict__ z,
    const float* __restrict__ emb, int* __restrict__ idxg,
    float* __restrict__ out_idx, int* __restrict__ hist,
    float* __restrict__ out_zq, double* __restrict__ part) {
#pragma clang fp contract(off)
  const int n = blockIdx.x;
  const int d = threadIdx.x;
  const int k = (int)(rkey[n] & 0xffffffffu);
  if (d == 0) {
    idxg[n] = k;
    out_idx[n] = (float)k;
    atomicAdd(&hist[k], 1);
  }
  const float zv = z[(size_t)n * kD + d];
  const float q = emb[(size_t)k * kD + d];
  out_zq[(size_t)n * kD + d] = zv + (q - zv);
  const float diff = zv - q;
  double v = (double)diff * (double)diff;
#pragma unroll
  for (int m = 32; m; m >>= 1) v += __shfl_xor(v, m);
  __shared__ double p4[4];
  if ((d & 63) == 0) p4[d >> 6] = v;
  __syncthreads();
  if (d == 0) part[n] = p4[0] + p4[1] + p4[2] + p4[3];
}

// ---------------- pre-reduce commit partials: 32768 -> 64 ------------------
__global__ __launch_bounds__(256) void reduce_part(
    const double* __restrict__ part, double* __restrict__ part2) {
#pragma clang fp contract(off)
  const int b = blockIdx.x;  // 64
  const int tid = threadIdx.x;
  double s = part[b * 512 + tid] + part[b * 512 + 256 + tid];
#pragma unroll
  for (int m = 32; m; m >>= 1) s += __shfl_xor(s, m);
  __shared__ double p4[4];
  if ((tid & 63) == 0) p4[tid >> 6] = s;
  __syncthreads();
  if (tid == 0) part2[b] = p4[0] + p4[1] + p4[2] + p4[3];
}

// ---------------- single-block: commit reduce + newcount + nsum + prefix ----
__global__ __launch_bounds__(256) void mid_k(
    const double* __restrict__ part2, float* __restrict__ out_com,
    const int* __restrict__ hist, const float* __restrict__ ec,
    float* __restrict__ out_cnt, double* __restrict__ nsum,
    int* __restrict__ offs, int* __restrict__ cursor) {
#pragma clang fp contract(off)
  const int t = threadIdx.x;
  __shared__ double dtmp[4];
  __shared__ int itmp[256];

  double s = (t < 64) ? part2[t] : 0.0;
#pragma unroll
  for (int m = 32; m; m >>= 1) s += __shfl_xor(s, m);
  if ((t & 63) == 0) dtmp[t >> 6] = s;
  __syncthreads();
  if (t == 0)
    out_com[0] = (float)(0.25 * (dtmp[0] + dtmp[1] + dtmp[2] + dtmp[3]) /
                         (double)((size_t)kN * kD));
  __syncthreads();

  const int base = t * 32;
  double ns = 0.0;
  int run = 0;
  for (int c = 0; c < 32; ++c) {
    const int k = base + c;
    const float nc = 0.99f * ec[k] + 0.01f * (float)hist[k];
    out_cnt[k] = nc;
    ns += (double)nc;
    run += hist[k];
  }
  itmp[t] = run;
  __syncthreads();
  for (int off = 1; off < 256; off <<= 1) {
    const int add = (t >= off) ? itmp[t - off] : 0;
    __syncthreads();
    itmp[t] += add;
    __syncthreads();
  }
  int run2 = itmp[t] - run;
  for (int c = 0; c < 32; ++c) {
    const int k = base + c;
    offs[k] = run2;
    cursor[k] = run2;
    run2 += hist[k];
  }
#pragma unroll
  for (int m = 32; m; m >>= 1) ns += __shfl_xor(ns, m);
  if ((t & 63) == 0) dtmp[t >> 6] = ns;
  __syncthreads();
  if (t == 0) *nsum = dtmp[0] + dtmp[1] + dtmp[2] + dtmp[3];
}

// ---------------- scatter rows into per-code lists ----------------
__global__ __launch_bounds__(256) void scatter_k(const int* __restrict__ idxg,
                                                 int* __restrict__ cursor,
                                                 int* __restrict__ rowlist) {
  const int r = blockIdx.x * 256 + threadIdx.x;
  const int k = idxg[r];
  const int pos = atomicAdd(&cursor[k], 1);
  rowlist[pos] = r;
}

// ---------------- new_avg + new_embed via gathered row sums ----------------
__global__ __launch_bounds__(256) void newavg_k(
    const float* __restrict__ z, const float* __restrict__ ea,
    const int* __restrict__ hist, const int* __restrict__ offs,
    const int* __restrict__ rowlist, const float* __restrict__ out_cnt,
    const double* __restrict__ nsum, float* __restrict__ out_emb,
    float* __restrict__ out_avg) {
#pragma clang fp contract(off)
  const int k = blockIdx.x;
  const int d = threadIdx.x;
  const int c = hist[k];
  const int off = offs[k];
  float s = 0.f;
  for (int j = 0; j < c; ++j)
    s += z[(size_t)rowlist[off + j] * kD + d];
  const size_t o = (size_t)k * kD + d;
  const float na = 0.99f * ea[o] + 0.01f * s;
  out_avg[o] = na;
  const float nf = (float)(*nsum);
  const float nc = out_cnt[k];
  const float keps = 0.08192f;  // fl(K * EPS)
  const float cs = (nc + 1e-5f) / (nf + keps) * nf;
  out_emb[o] = na / cs;
}

extern "C" void kernel_launch(void* const* d_in, const int* in_sizes, int n_in,
                              void* d_out, int out_size, void* d_ws, size_t ws_size,
                              hipStream_t stream) {
  const float* z_e       = (const float*)d_in[0];
  const float* embedding = (const float*)d_in[1];
  const float* ema_count = (const float*)d_in[2];
  const float* ema_avg   = (const float*)d_in[3];

  char* ws = (char*)d_ws;
  int*    hist   = (int*)(ws + OFF_HIST);
  double* nsum   = (double*)(ws + OFF_NS);
  unsigned* segcnt = (unsigned*)(ws + OFF_SEG);
  unsigned* tcnt = (unsigned*)(ws + OFF_TCNT);
  unsigned long long* rkey = (unsigned long long*)(ws + OFF_RKEY);
  float*  sz     = (float*)(ws + OFF_SZ);
  float*  cw     = (float*)(ws + OFF_CW);
  float*  thrv   = (float*)(ws + OFF_THR);
  _Float16* z16  = (_Float16*)(ws + OFF_Z16);
  _Float16* w16  = (_Float16*)(ws + OFF_W16);
  float*  tmin   = (float*)(ws + OFF_TMIN);
  int2*   flat   = (int2*)(ws + OFF_FLAT);
  int*    tlist  = (int*)(ws + OFF_TLIST);
  int*    idxg   = (int*)(ws + OFF_IDX);
  int*    offs   = (int*)(ws + OFF_OFFS);
  int*    cursor = (int*)(ws + OFF_CUR);
  int*    rowlist= (int*)(ws + OFF_ROWL);
  double* part   = (double*)(ws + OFF_PART);
  double* part2  = (double*)(ws + OFF_PART2);

  float* out_zq  = (float*)d_out;
  float* out_com = out_zq + (size_t)kN * kD;
  float* out_idx = out_com + 1;
  float* out_emb = out_idx + kN;
  float* out_cnt = out_emb + (size_t)kK * kD;
  float* out_avg = out_cnt + kK;

  prep2<<<1280, 256, 0, stream>>>(z_e, embedding, z16, w16, sz, cw, hist,
                                  segcnt, tcnt, rkey);
  score_min<<<(kN / 128) * (kK / 128), 256, 0, stream>>>(z16, w16, cw, tmin);
  rowmin_k<<<kN / 64, 256, 0, stream>>>(tmin, thrv);
  append_k<<<NTIL * 8, 256, 0, stream>>>(tmin, thrv, tcnt, tlist);
  score_gather<<<NTIL * JSLOT, 256, 0, stream>>>(z16, w16, cw, thrv, tcnt,
                                                 tlist, segcnt, flat);
  exact_kernel<<<(NSEG * SEGCAP) / 256, 256, 0, stream>>>(
      z_e, embedding, sz, cw, flat, segcnt, rkey);
  finalize_zq<<<kN, 256, 0, stream>>>(rkey, z_e, embedding, idxg, out_idx,
                                      hist, out_zq, part);
  reduce_part<<<64, 256, 0, stream>>>(part, part2);
  mid_k<<<1, 256, 0, stream>>>(part2, out_com, hist, ema_count, out_cnt, nsum,
                               offs, cursor);
  scatter_k<<<kN / 256, 256, 0, stream>>>(idxg, cursor, rowlist);
  newavg_k<<<kK, 256, 0, stream>>>(z_e, ema_avg, hist, offs, rowlist, out_cnt,
                                   nsum, out_emb, out_avg);
}

// Round 10
// 413.229 us; speedup vs baseline: 1.5643x; 1.3717x over previous
//
#include <hip/hip_runtime.h>

// VectorQuantizerEMA  N=32768 K=8192 D=256  fp32
// Outputs: z_q_st[N*D], commitment[1], idx[N], new_embed[K*D], new_count[K], new_avg[K*D]
//
// Single full fp16 MFMA score GEMM (z16 * (w*2^14)16):
//   prep2:     fp16 convert + numpy-order row sums + workspace init
//              (hist/tcnt zero, rkey 0xFF) - no memsets.
//   score_min: 128x128 tile, BK=64, 4 waves, 2-barrier K-loop (r5-best:
//              196.9us). STRUCTURE-BOUND at ~197us: r6 8-phase port (276us,
//              4 K-tiles can't fill pipeline), r7 LDS-shrink (208us), r8
//              XCD-banding (201us, FETCH 160->27MB, time flat) all failed.
//              Per-(row,128-code-tile) min -> tmin[ntile][row].
//   rowmin_k:  thr[m] = min over 64 tile-mins + WWIN.
//   append_k:  512 blocks: 16-bit survivor masks, block prefix-scan, ONE
//              global atomicAdd per block.
//   score_gather: gathered-row 128x128 MFMA re-score ONLY for surviving pairs
//              (same per-fragment K-chain -> bit-identical scores); for each
//              candidate, INLINE exact fp32-chain dist (identical fmaf chain,
//              contract-off) -> atomicMin rkey. No flat list, no segcnt, no
//              separate exact kernel.
// Then finalize (idx/hist/z_q/commit partials), EMA epilogue via inverted
// index. rkey atomicMin (fmap(dist)<<32|n) = numpy first-index tie-break.
//
// Candidate-set equivalence: s(m,n) <= thr(m) implies tilemin(m,tile(n)) <=
// s <= thr, so the tile survives and (m,n) is enumerated by score_gather with
// the bit-identical s -> identical candidate set to the two-full-pass scheme.
// atomicMin order-independent.

typedef _Float16 half8 __attribute__((ext_vector_type(8)));
typedef _Float16 half4 __attribute__((ext_vector_type(4)));
typedef __attribute__((ext_vector_type(4))) float floatx4;

namespace {
constexpr int kN = 32768;
constexpr int kK = 8192;
constexpr int kD = 256;
constexpr int NTIL = kK / 128;     // 64 code tiles
constexpr int JSLOT = 32;          // chunk-slots per tile in score_gather
constexpr float WWIN = 2.0e-4f;    // containment needs ~8.5e-5; 2.3x margin

// ---- workspace layout (bytes) ----
constexpr size_t OFF_HIST = 0;                                // int K
constexpr size_t OFF_NS   = OFF_HIST + (size_t)kK * 4;        // double
constexpr size_t OFF_TCNT = OFF_NS + 8;                       // uint NTIL
constexpr size_t OFF_RKEY = (OFF_TCNT + (size_t)NTIL * 4 + 63) & ~(size_t)63;
constexpr size_t OFF_SZ   = OFF_RKEY + (size_t)kN * 8;        // float N
constexpr size_t OFF_CW   = OFF_SZ + (size_t)kN * 4;          // float K
constexpr size_t OFF_THR  = OFF_CW + (size_t)kK * 4;          // float N
constexpr size_t OFF_Z16  = OFF_THR + (size_t)kN * 4;         // f16 N*D
constexpr size_t OFF_W16  = OFF_Z16 + (size_t)kN * kD * 2;    // f16 K*D
constexpr size_t OFF_TMIN = OFF_W16 + (size_t)kK * kD * 2;    // float NTIL*N
constexpr size_t OFF_TLIST = OFF_TMIN + (size_t)NTIL * kN * 4; // int NTIL*N
constexpr size_t OFF_IDX  = OFF_TLIST + (size_t)NTIL * kN * 4; // int N
constexpr size_t OFF_OFFS = OFF_IDX + (size_t)kN * 4;         // int K
constexpr size_t OFF_CUR  = OFF_OFFS + (size_t)kK * 4;        // int K
constexpr size_t OFF_ROWL = OFF_CUR + (size_t)kK * 4;         // int N
constexpr size_t OFF_PART = OFF_ROWL + (size_t)kN * 4;        // double N
constexpr size_t OFF_PART2 = OFF_PART + (size_t)kN * 8;       // double 64
} // namespace

__device__ __forceinline__ unsigned fmap(float f) {
  unsigned u = __float_as_uint(f);
  return (u & 0x80000000u) ? ~u : (u | 0x80000000u);
}
__device__ __forceinline__ void gload16(const void* g, void* l) {
  __builtin_amdgcn_global_load_lds(
      (const __attribute__((address_space(1))) unsigned int*)g,
      (__attribute__((address_space(3))) unsigned int*)l, 16, 0, 0);
}

// exact fp32-chain dist (bit-exact vs numpy/OpenBLAS) + rkey atomicMin
__device__ void exact_insert(const float* __restrict__ zrow,
                             const float* __restrict__ wrow, float szm,
                             float cwn, int n,
                             unsigned long long* __restrict__ rk) {
#pragma clang fp contract(off)
  float a = 0.f;
  for (int d4 = 0; d4 < kD; d4 += 4) {
    const float4 zv = *(const float4*)&zrow[d4];
    const float4 wv = *(const float4*)&wrow[d4];
    a = __builtin_fmaf(zv.x, wv.x, a);
    a = __builtin_fmaf(zv.y, wv.y, a);
    a = __builtin_fmaf(zv.z, wv.z, a);
    a = __builtin_fmaf(zv.w, wv.w, a);
  }
  const float u = szm - 2.0f * a;
  const float dist = u + cwn;
  const unsigned long long key =
      ((unsigned long long)fmap(dist) << 32) | (unsigned)n;
  atomicMin(rk, key);  // equal dist -> lower n (numpy first-index)
}

// ---------------- numpy AVX512 pairwise sum of squares ----------------
__device__ __forceinline__ float pw_block128_sq(const float* __restrict__ p) {
#pragma clang fp contract(off)
  float u[16];
#pragma unroll
  for (int l = 0; l < 16; ++l) {
    const float x0 = p[l] * p[l];
    const float x1 = p[16 + l] * p[16 + l];
    const float x2 = p[32 + l] * p[32 + l];
    const float x3 = p[48 + l] * p[48 + l];
    const float x4 = p[64 + l] * p[64 + l];
    const float x5 = p[80 + l] * p[80 + l];
    const float x6 = p[96 + l] * p[96 + l];
    const float x7 = p[112 + l] * p[112 + l];
    u[l] = ((x0 + x1) + (x2 + x3)) + ((x4 + x5) + (x6 + x7));
  }
  float t1[8], t2[4], t3[2];
#pragma unroll
  for (int l = 0; l < 8; ++l) t1[l] = u[l] + u[l + 8];
#pragma unroll
  for (int l = 0; l < 4; ++l) t2[l] = t1[l] + t1[l + 4];
#pragma unroll
  for (int l = 0; l < 2; ++l) t3[l] = t2[l] + t2[l + 2];
  return t3[0] + t3[1];
}

// ------- fused fp16 convert + numpy-order row sums + workspace init -------
__global__ __launch_bounds__(256) void prep2(
    const float* __restrict__ z, const float* __restrict__ w,
    _Float16* __restrict__ z16, _Float16* __restrict__ w16,
    float* __restrict__ sz, float* __restrict__ cw, int* __restrict__ hist,
    unsigned* __restrict__ tcnt, unsigned long long* __restrict__ rkey) {
  const int g = blockIdx.x * 256 + threadIdx.x;
  if (g < kN) rkey[g] = ~0ull;
  if (g < kK) hist[g] = 0;
  if (g < NTIL) tcnt[g] = 0;

  const bool isz = (blockIdx.x < 1024);
  const int b = isz ? blockIdx.x : blockIdx.x - 1024;
  const int nblocks = isz ? 1024 : 256;
  const int nrows = isz ? kN : kK;
  const float scale = isz ? 1.0f : 16384.0f;
  const float* x = isz ? z : w;
  _Float16* out16 = isz ? z16 : w16;
  float* sums = isz ? sz : cw;

  const int gid = b * 256 + threadIdx.x;
  const int gtot = nblocks * 256;
  const int nf4 = nrows * (kD / 4);
  for (int i = gid; i < nf4; i += gtot) {
    const float4 v = ((const float4*)x)[i];
    half4 h;
    h.x = (_Float16)(v.x * scale);
    h.y = (_Float16)(v.y * scale);
    h.z = (_Float16)(v.z * scale);
    h.w = (_Float16)(v.w * scale);
    ((half4*)out16)[i] = h;
  }
  for (int r = gid; r < nrows; r += gtot) {
    const float* p = x + (size_t)r * kD;
    sums[r] = pw_block128_sq(p) + pw_block128_sq(p + 128);
  }
}

// ---------------- MFMA score pass: 128x128 tile, BK=64 ---------------------
__global__ __launch_bounds__(256, 4) void score_min(
    const _Float16* __restrict__ z16, const _Float16* __restrict__ w16,
    const float* __restrict__ cw, float* __restrict__ tmin) {
  __shared__ _Float16 As[128 * 64];  // 16 KB, XOR-swizzled 16B chunks (8/row)
  __shared__ _Float16 Bs[128 * 64];  // 16 KB
  __shared__ unsigned pairmin[4][64];

  const int tid = threadIdx.x;
  const int wid = tid >> 6;
  const int lane = tid & 63;
  const int l16 = lane & 15;
  const int quad = lane >> 4;
  const int m0 = (blockIdx.x & 255) * 128;
  const int nt0 = blockIdx.x >> 8;
  const int n0 = nt0 * 128;
  const int rowbase = (wid >> 1) * 64;
  const int colbase = (wid & 1) * 64;

  floatx4 acc[4][4];
#pragma unroll
  for (int a = 0; a < 4; ++a)
#pragma unroll
    for (int b = 0; b < 4; ++b) acc[a][b] = (floatx4){0.f, 0.f, 0.f, 0.f};

  for (int kt = 0; kt < 4; ++kt) {
    const int d0 = kt * 64;
    __syncthreads();  // prior-iter LDS reads complete before overwrite
#pragma unroll
    for (int p = 0; p < 4; ++p) {  // A: 128 rows x 64 d
      const int q = p * 4 + wid;
      const int r = q * 8 + (lane >> 3);
      const int c = (lane & 7) ^ (r & 7);
      gload16(z16 + (size_t)(m0 + r) * kD + d0 + c * 8, &As[q * 512]);
    }
#pragma unroll
    for (int p = 0; p < 4; ++p) {  // B: 128 codes x 64 d
      const int q = p * 4 + wid;
      const int r = q * 8 + (lane >> 3);
      const int c = (lane & 7) ^ (r & 7);
      gload16(w16 + (size_t)(n0 + r) * kD + d0 + c * 8, &Bs[q * 512]);
    }
    __syncthreads();  // drain staging
#pragma unroll
    for (int kc = 0; kc < 2; ++kc) {
      half8 af[4], bfr[4];
#pragma unroll
      for (int mt = 0; mt < 4; ++mt) {
        const int row = rowbase + mt * 16 + l16;
        const int j = (kc * 4 + quad) ^ (row & 7);
        af[mt] = *(const half8*)&As[row * 64 + j * 8];
      }
#pragma unroll
      for (int nt = 0; nt < 4; ++nt) {
        const int row = colbase + nt * 16 + l16;
        const int j = (kc * 4 + quad) ^ (row & 7);
        bfr[nt] = *(const half8*)&Bs[row * 64 + j * 8];
      }
#pragma unroll
      for (int mt = 0; mt < 4; ++mt)
#pragma unroll
        for (int nt = 0; nt < 4; ++nt)
          acc[mt][nt] = __builtin_amdgcn_mfma_f32_16x16x32_f16(
              af[mt], bfr[nt], acc[mt][nt], 0, 0, 0);
    }
  }

  // ---- scores: w scaled by 2^14 -> -2*2^-14 = -2^-13 exactly ----
  float cwv[4];
#pragma unroll
  for (int nt = 0; nt < 4; ++nt)
    cwv[nt] = cw[n0 + colbase + nt * 16 + l16];

  // block row-min over this block's 128 codes -> tmin[nt0][row]
#pragma unroll
  for (int mt = 0; mt < 4; ++mt)
#pragma unroll
    for (int r = 0; r < 4; ++r) {
      float mn = 3.4e38f;
#pragma unroll
      for (int nt = 0; nt < 4; ++nt)
        mn = fminf(mn, fmaf(acc[mt][nt][r], -1.220703125e-4f, cwv[nt]));
#pragma unroll
      for (int off = 1; off < 16; off <<= 1)
        mn = fminf(mn, __shfl_xor(mn, off));
      if (l16 == 0) pairmin[wid][mt * 16 + quad * 4 + r] = fmap(mn);
    }
  __syncthreads();
  if ((wid & 1) == 0) {
    const unsigned v = min(pairmin[wid][lane], pairmin[wid + 1][lane]);
    const unsigned u = (v & 0x80000000u) ? (v & 0x7fffffffu) : ~v;
    tmin[(size_t)nt0 * kN + m0 + rowbase + lane] = __uint_as_float(u);
  }
}

// ---------------- row thresholds (no atomics) ------------------------------
__global__ __launch_bounds__(256) void rowmin_k(const float* __restrict__ tmin,
                                                float* __restrict__ thrv) {
  const int tid = threadIdx.x;
  const int w = tid >> 6;            // tile quarter 0..3
  const int lane = tid & 63;
  const int m = blockIdx.x * 64 + lane;

  float v[16];
#pragma unroll
  for (int i = 0; i < 16; ++i)
    v[i] = tmin[(size_t)(w * 16 + i) * kN + m];

  float mn = fminf(v[0], v[1]);
#pragma unroll
  for (int i = 2; i < 16; ++i) mn = fminf(mn, v[i]);

  __shared__ float red[4][64];
  red[w][lane] = mn;
  __syncthreads();
  if (w == 0)
    thrv[m] = fminf(fminf(red[0][lane], red[1][lane]),
                    fminf(red[2][lane], red[3][lane])) + WWIN;
}

// ---------------- survivor-list build (one atomic per block) ---------------
__global__ __launch_bounds__(256) void append_k(const float* __restrict__ tmin,
                                                const float* __restrict__ thrv,
                                                unsigned* __restrict__ tcnt,
                                                int* __restrict__ tlist) {
  const int t = blockIdx.x >> 3;
  const int slice = blockIdx.x & 7;
  const int tid = threadIdx.x;
  const int m0 = slice * (kN / 8);
  const float* tm = tmin + (size_t)t * kN;

  unsigned okbits = 0;
#pragma unroll
  for (int it = 0; it < 16; ++it) {
    const int m = m0 + it * 256 + tid;
    if (tm[m] <= thrv[m]) okbits |= (1u << it);
  }
  const int cnt = __popc(okbits);

  __shared__ int itmp[256];
  __shared__ int sbase;
  itmp[tid] = cnt;
  __syncthreads();
  for (int off = 1; off < 256; off <<= 1) {
    const int add = (tid >= off) ? itmp[tid - off] : 0;
    __syncthreads();
    itmp[tid] += add;
    __syncthreads();
  }
  if (tid == 255) sbase = (int)atomicAdd(&tcnt[t], (unsigned)itmp[255]);
  __syncthreads();

  int pos = sbase + itmp[tid] - cnt;
  int* tl = tlist + (size_t)t * kN;
#pragma unroll
  for (int it = 0; it < 16; ++it)
    if ((okbits >> it) & 1u) tl[pos++] = m0 + it * 256 + tid;
}

// ---------------- gathered-row MFMA re-score + inline exact dist -----------
// grid NTIL*JSLOT: block (t, j0) processes chunks j0, j0+JSLOT, ... of tile
// t's row list (128 gathered rows x 128 codes each). Same MFMA accumulation
// order as score_min -> bit-identical scores. Candidates resolved IN PLACE:
// exact fp32-chain dist + atomicMin rkey (order-independent).
__global__ __launch_bounds__(256, 4) void score_gather(
    const _Float16* __restrict__ z16, const _Float16* __restrict__ w16,
    const float* __restrict__ cw, const float* __restrict__ thrv,
    const unsigned* __restrict__ tcnt, const int* __restrict__ tlist,
    const float* __restrict__ zf, const float* __restrict__ emb,
    const float* __restrict__ sz, unsigned long long* __restrict__ rkey) {
  __shared__ _Float16 Asg[128 * 64];
  __shared__ _Float16 Bsg[128 * 64];

  const int tid = threadIdx.x;
  const int wid = tid >> 6;
  const int lane = tid & 63;
  const int l16 = lane & 15;
  const int quad = lane >> 4;
  const int t = blockIdx.x & (NTIL - 1);
  const int j0 = blockIdx.x >> 6;  // 0..JSLOT-1
  const int n0 = t * 128;
  const int rowbase = (wid >> 1) * 64;
  const int colbase = (wid & 1) * 64;
  const int ct = (int)tcnt[t];
  if (j0 * 128 >= ct) return;
  const int* rlist = tlist + (size_t)t * kN;

  float cwv[4];
#pragma unroll
  for (int nt = 0; nt < 4; ++nt)
    cwv[nt] = cw[n0 + colbase + nt * 16 + l16];

  for (int chunk = j0; chunk * 128 < ct; chunk += JSLOT) {
    const int base = chunk * 128;
    floatx4 acc[4][4];
#pragma unroll
    for (int a = 0; a < 4; ++a)
#pragma unroll
      for (int b = 0; b < 4; ++b) acc[a][b] = (floatx4){0.f, 0.f, 0.f, 0.f};

    for (int kt = 0; kt < 4; ++kt) {
      const int d0 = kt * 64;
      __syncthreads();
#pragma unroll
      for (int p = 0; p < 4; ++p) {  // A: 128 gathered rows x 64 d
        const int q = p * 4 + wid;
        const int r = q * 8 + (lane >> 3);
        const int c = (lane & 7) ^ (r & 7);
        int gi = base + r;
        if (gi >= ct) gi = base;  // pad with dup of first row in chunk
        gload16(z16 + (size_t)rlist[gi] * kD + d0 + c * 8, &Asg[q * 512]);
      }
#pragma unroll
      for (int p = 0; p < 4; ++p) {  // B: 128 codes x 64 d
        const int q = p * 4 + wid;
        const int r = q * 8 + (lane >> 3);
        const int c = (lane & 7) ^ (r & 7);
        gload16(w16 + (size_t)(n0 + r) * kD + d0 + c * 8, &Bsg[q * 512]);
      }
      __syncthreads();
#pragma unroll
      for (int kc = 0; kc < 2; ++kc) {
        half8 af[4], bfr[4];
#pragma unroll
        for (int mt = 0; mt < 4; ++mt) {
          const int row = rowbase + mt * 16 + l16;
          const int j = (kc * 4 + quad) ^ (row & 7);
          af[mt] = *(const half8*)&Asg[row * 64 + j * 8];
        }
#pragma unroll
        for (int nt = 0; nt < 4; ++nt) {
          const int row = colbase + nt * 16 + l16;
          const int j = (kc * 4 + quad) ^ (row & 7);
          bfr[nt] = *(const half8*)&Bsg[row * 64 + j * 8];
        }
#pragma unroll
        for (int mt = 0; mt < 4; ++mt)
#pragma unroll
          for (int nt = 0; nt < 4; ++nt)
            acc[mt][nt] = __builtin_amdgcn_mfma_f32_16x16x32_f16(
                af[mt], bfr[nt], acc[mt][nt], 0, 0, 0);
      }
    }

    // ---- candidate mask (padded rows gi>=ct gated out) ----
    unsigned long long cmask = 0ull;
#pragma unroll
    for (int mt = 0; mt < 4; ++mt) {
#pragma unroll
      for (int r = 0; r < 4; ++r) {
        const int gi = base + rowbase + mt * 16 + quad * 4 + r;
        const bool vrow = (gi < ct);
        const int m = rlist[vrow ? gi : base];
        const float th = thrv[m];
#pragma unroll
        for (int nt = 0; nt < 4; ++nt) {
          const float s = fmaf(acc[mt][nt][r], -1.220703125e-4f, cwv[nt]);
          if (vrow && s <= th)
            cmask |= 1ull << (mt * 16 + r * 4 + nt);
        }
      }
    }
    // ---- resolve candidates in place (single exact-chain code copy) ----
    while (cmask) {
      const int b = __ffsll((long long)cmask) - 1;
      cmask &= cmask - 1;
      const int mt = b >> 4, r = (b >> 2) & 3, nt = b & 3;
      const int m = rlist[base + rowbase + mt * 16 + quad * 4 + r];
      const int n = n0 + colbase + nt * 16 + l16;
      exact_insert(zf + (size_t)m * kD, emb + (size_t)n * kD, sz[m], cw[n], n,
                   &rkey[m]);
    }
  }
}

// ------- finalize idx + hist + z_q_st + commit partials (warp/row) --------
__global__ __launch_bounds__(256) void finalize_zq(
    const unsigned long long* __restrict__ rkey, const float* __restrict__ z,
    const float* __restrict__ emb, int* __restrict__ idxg,
    float* __restrict__ out_idx, int* __restrict__ hist,
    float* __restrict__ out_zq, double* __restrict__ part) {
#pragma clang fp contract(off)
  const int tid = threadIdx.x;
  const int n = blockIdx.x * 4 + (tid >> 6);
  const int lane = tid & 63;
  const int k = (int)(rkey[n] & 0xffffffffu);
  if (lane == 0) {
    idxg[n] = k;
    out_idx[n] = (float)k;
    atomicAdd(&hist[k], 1);
  }
  const float4 zv = *(const float4*)&z[(size_t)n * kD + lane * 4];
  const float4 qv = *(const float4*)&emb[(size_t)k * kD + lane * 4];
  float4 o;
  o.x = zv.x + (qv.x - zv.x);
  o.y = zv.y + (qv.y - zv.y);
  o.z = zv.z + (qv.z - zv.z);
  o.w = zv.w + (qv.w - zv.w);
  *(float4*)&out_zq[(size_t)n * kD + lane * 4] = o;
  const float dx = zv.x - qv.x, dy = zv.y - qv.y;
  const float dz = zv.z - qv.z, dw = zv.w - qv.w;
  double v = ((double)dx * dx + (double)dy * dy) +
             ((double)dz * dz + (double)dw * dw);
#pragma unroll
  for (int m = 32; m; m >>= 1) v += __shfl_xor(v, m);
  if (lane == 0) part[n] = v;
}

// ---------------- pre-reduce commit partials: 32768 -> 64 ------------------
__global__ __launch_bounds__(256) void reduce_part(
    const double* __restrict__ part, double* __restrict__ part2) {
#pragma clang fp contract(off)
  const int b = blockIdx.x;  // 64
  const int tid = threadIdx.x;
  double s = part[b * 512 + tid] + part[b * 512 + 256 + tid];
#pragma unroll
  for (int m = 32; m; m >>= 1) s += __shfl_xor(s, m);
  __shared__ double p4[4];
  if ((tid & 63) == 0) p4[tid >> 6] = s;
  __syncthreads();
  if (tid == 0) part2[b] = p4[0] + p4[1] + p4[2] + p4[3];
}

// ---------------- single-block: commit reduce + newcount + nsum + prefix ----
__global__ __launch_bounds__(256) void mid_k(
    const double* __restrict__ part2, float* __restrict__ out_com,
    const int* __restrict__ hist, const float* __restrict__ ec,
    float* __restrict__ out_cnt, double* __restrict__ nsum,
    int* __restrict__ offs, int* __restrict__ cursor) {
#pragma clang fp contract(off)
  const int t = threadIdx.x;
  __shared__ double dtmp[4];
  __shared__ int itmp[256];

  double s = (t < 64) ? part2[t] : 0.0;
#pragma unroll
  for (int m = 32; m; m >>= 1) s += __shfl_xor(s, m);
  if ((t & 63) == 0) dtmp[t >> 6] = s;
  __syncthreads();
  if (t == 0)
    out_com[0] = (float)(0.25 * (dtmp[0] + dtmp[1] + dtmp[2] + dtmp[3]) /
                         (double)((size_t)kN * kD));
  __syncthreads();

  const int base = t * 32;
  double ns = 0.0;
  int run = 0;
  for (int c = 0; c < 32; ++c) {
    const int k = base + c;
    const float nc = 0.99f * ec[k] + 0.01f * (float)hist[k];
    out_cnt[k] = nc;
    ns += (double)nc;
    run += hist[k];
  }
  itmp[t] = run;
  __syncthreads();
  for (int off = 1; off < 256; off <<= 1) {
    const int add = (t >= off) ? itmp[t - off] : 0;
    __syncthreads();
    itmp[t] += add;
    __syncthreads();
  }
  int run2 = itmp[t] - run;
  for (int c = 0; c < 32; ++c) {
    const int k = base + c;
    offs[k] = run2;
    cursor[k] = run2;
    run2 += hist[k];
  }
#pragma unroll
  for (int m = 32; m; m >>= 1) ns += __shfl_xor(ns, m);
  if ((t & 63) == 0) dtmp[t >> 6] = ns;
  __syncthreads();
  if (t == 0) *nsum = dtmp[0] + dtmp[1] + dtmp[2] + dtmp[3];
}

// ---------------- scatter rows into per-code lists ----------------
__global__ __launch_bounds__(256) void scatter_k(const int* __restrict__ idxg,
                                                 int* __restrict__ cursor,
                                                 int* __restrict__ rowlist) {
  const int r = blockIdx.x * 256 + threadIdx.x;
  const int k = idxg[r];
  const int pos = atomicAdd(&cursor[k], 1);
  rowlist[pos] = r;
}

// -------- new_avg + new_embed via gathered row sums (warp/code) -----------
__global__ __launch_bounds__(256) void newavg_k(
    const float* __restrict__ z, const float* __restrict__ ea,
    const int* __restrict__ hist, const int* __restrict__ offs,
    const int* __restrict__ rowlist, const float* __restrict__ out_cnt,
    const double* __restrict__ nsum, float* __restrict__ out_emb,
    float* __restrict__ out_avg) {
#pragma clang fp contract(off)
  const int k = blockIdx.x * 4 + (threadIdx.x >> 6);
  const int lane = threadIdx.x & 63;
  const int c = hist[k];
  const int off = offs[k];
  float4 s = {0.f, 0.f, 0.f, 0.f};
  for (int j = 0; j < c; ++j) {
    const float4 zv =
        *(const float4*)&z[(size_t)rowlist[off + j] * kD + lane * 4];
    s.x += zv.x;
    s.y += zv.y;
    s.z += zv.z;
    s.w += zv.w;
  }
  const size_t o = (size_t)k * kD + lane * 4;
  const float4 eav = *(const float4*)&ea[o];
  float4 na;
  na.x = 0.99f * eav.x + 0.01f * s.x;
  na.y = 0.99f * eav.y + 0.01f * s.y;
  na.z = 0.99f * eav.z + 0.01f * s.z;
  na.w = 0.99f * eav.w + 0.01f * s.w;
  *(float4*)&out_avg[o] = na;
  const float nf = (float)(*nsum);
  const float nc = out_cnt[k];
  const float keps = 0.08192f;  // fl(K * EPS)
  const float cs = (nc + 1e-5f) / (nf + keps) * nf;
  float4 oe;
  oe.x = na.x / cs;
  oe.y = na.y / cs;
  oe.z = na.z / cs;
  oe.w = na.w / cs;
  *(float4*)&out_emb[o] = oe;
}

extern "C" void kernel_launch(void* const* d_in, const int* in_sizes, int n_in,
                              void* d_out, int out_size, void* d_ws, size_t ws_size,
                              hipStream_t stream) {
  const float* z_e       = (const float*)d_in[0];
  const float* embedding = (const float*)d_in[1];
  const float* ema_count = (const float*)d_in[2];
  const float* ema_avg   = (const float*)d_in[3];

  char* ws = (char*)d_ws;
  int*    hist   = (int*)(ws + OFF_HIST);
  double* nsum   = (double*)(ws + OFF_NS);
  unsigned* tcnt = (unsigned*)(ws + OFF_TCNT);
  unsigned long long* rkey = (unsigned long long*)(ws + OFF_RKEY);
  float*  sz     = (float*)(ws + OFF_SZ);
  float*  cw     = (float*)(ws + OFF_CW);
  float*  thrv   = (float*)(ws + OFF_THR);
  _Float16* z16  = (_Float16*)(ws + OFF_Z16);
  _Float16* w16  = (_Float16*)(ws + OFF_W16);
  float*  tmin   = (float*)(ws + OFF_TMIN);
  int*    tlist  = (int*)(ws + OFF_TLIST);
  int*    idxg   = (int*)(ws + OFF_IDX);
  int*    offs   = (int*)(ws + OFF_OFFS);
  int*    cursor = (int*)(ws + OFF_CUR);
  int*    rowlist= (int*)(ws + OFF_ROWL);
  double* part   = (double*)(ws + OFF_PART);
  double* part2  = (double*)(ws + OFF_PART2);

  float* out_zq  = (float*)d_out;
  float* out_com = out_zq + (size_t)kN * kD;
  float* out_idx = out_com + 1;
  float* out_emb = out_idx + kN;
  float* out_cnt = out_emb + (size_t)kK * kD;
  float* out_avg = out_cnt + kK;

  prep2<<<1280, 256, 0, stream>>>(z_e, embedding, z16, w16, sz, cw, hist,
                                  tcnt, rkey);
  score_min<<<(kN / 128) * (kK / 128), 256, 0, stream>>>(z16, w16, cw, tmin);
  rowmin_k<<<kN / 64, 256, 0, stream>>>(tmin, thrv);
  append_k<<<NTIL * 8, 256, 0, stream>>>(tmin, thrv, tcnt, tlist);
  score_gather<<<NTIL * JSLOT, 256, 0, stream>>>(z16, w16, cw, thrv, tcnt,
                                                 tlist, z_e, embedding, sz,
                                                 rkey);
  finalize_zq<<<kN / 4, 256, 0, stream>>>(rkey, z_e, embedding, idxg, out_idx,
                                          hist, out_zq, part);
  reduce_part<<<64, 256, 0, stream>>>(part, part2);
  mid_k<<<1, 256, 0, stream>>>(part2, out_com, hist, ema_count, out_cnt, nsum,
                               offs, cursor);
  scatter_k<<<kN / 256, 256, 0, stream>>>(idxg, cursor, rowlist);
  newavg_k<<<kK / 4, 256, 0, stream>>>(z_e, ema_avg, hist, offs, rowlist,
                                       out_cnt, nsum, out_emb, out_avg);
}